// Round 9
// baseline (1115.818 us; speedup 1.0000x reference)
//
#include <hip/hip_runtime.h>
#include <hip/hip_bf16.h>
#include <math.h>

// ---------------- problem constants ----------------
#define BDIM 32
#define HDIM 56
#define WDIM 56
#define CDIM 384
#define NHEAD 12
#define WSZ 14
#define SSZ 7
#define LDIM (HDIM*WDIM)        // 3136
#define NTOK (WSZ*WSZ)          // 196
#define HDHEAD (CDIM/NHEAD)     // 32
#define HIDDIM (4*CDIM)         // 1536
#define NWIN 16
#define BWIN (BDIM*NWIN)        // 512
#define MROWS (BDIM*LDIM)       // 100352 == BWIN*NTOK
#define EPSLN 1e-5f
#define ATTSCALE 0.17677669529663687f   // 32^-0.5

// padded LDS strides (shorts) for attention
#define KROW 40
#define VROW 232
#define PROW 232

typedef __hip_bfloat16 bf16;
typedef __attribute__((ext_vector_type(8))) short bf16x8;   // 8 bf16 = 4 VGPRs
typedef __attribute__((ext_vector_type(4))) short s16x4;    // 4 bf16 = 1 b64 store
typedef __attribute__((ext_vector_type(4))) float f32x4;

// async global->LDS, 16B per lane, wave-uniform LDS base
#define ASYNC16(gp, lp) __builtin_amdgcn_global_load_lds( \
    (__attribute__((address_space(1))) void*)(gp),        \
    (__attribute__((address_space(3))) void*)(lp), 16, 0, 0)

// float -> bf16 bit pattern as short (type-consistent with short LDS arrays)
static __device__ __forceinline__ short f2bfs(float x) {
  union { bf16 h; short s; } u; u.h = __float2bfloat16(x); return u.s;
}
static __device__ __forceinline__ float bfs2f(short s) {
  unsigned int u = ((unsigned int)(unsigned short)s) << 16;
  float f; __builtin_memcpy(&f, &u, 4); return f;
}
static __device__ __forceinline__ float tof(float x) { return x; }
static __device__ __forceinline__ float tof(bf16 x)  { return __bfloat162float(x); }

// ---------------- fp32 -> bf16 weight convert ----------------
__global__ __launch_bounds__(256) void k_cvt(const float* __restrict__ in,
                                             bf16* __restrict__ out, int n)
{
  int i = blockIdx.x * 256 + threadIdx.x;
  if (i < n) out[i] = __float2bfloat16(in[i]);
}

// ---------------- LN (+optional shift-roll + window partition) ----------------
template<bool WIN, typename TIN>
__global__ __launch_bounds__(128) void k_ln(const TIN* __restrict__ xin,
    const float* __restrict__ gw, const float* __restrict__ gb,
    bf16* __restrict__ out)
{
  int r = blockIdx.x;
  int t = threadIdx.x;
  const TIN* xp = xin + (size_t)r * CDIM;
  float v0 = tof(xp[t]), v1 = tof(xp[t+128]), v2 = tof(xp[t+256]);
  float s  = v0+v1+v2;
  float ss = v0*v0 + v1*v1 + v2*v2;
  #pragma unroll
  for (int o = 32; o > 0; o >>= 1) { s += __shfl_down(s, o); ss += __shfl_down(ss, o); }
  __shared__ float red[4];
  if ((t & 63) == 0) { red[(t>>6)*2] = s; red[(t>>6)*2+1] = ss; }
  __syncthreads();
  float mean = (red[0]+red[2]) * (1.0f/CDIM);
  float var  = (red[1]+red[3]) * (1.0f/CDIM) - mean*mean;
  float rstd = rsqrtf(var + EPSLN);

  size_t orow;
  if (WIN) {
    int b = r / LDIM, l = r % LDIM;
    int h = l / WDIM, w = l % WDIM;
    int h2 = (h + HDIM - SSZ) % HDIM, w2 = (w + WDIM - SSZ) % WDIM;
    int wh = h2 / WSZ, ii = h2 % WSZ, ww = w2 / WSZ, jj = w2 % WSZ;
    int b_ = b*NWIN + wh*4 + ww;
    int n  = ii*WSZ + jj;
    orow = ((size_t)b_*NTOK + n) * CDIM;
  } else {
    orow = (size_t)r * CDIM;
  }
  out[orow+t]     = __float2bfloat16((v0-mean)*rstd*gw[t]     + gb[t]);
  out[orow+t+128] = __float2bfloat16((v1-mean)*rstd*gw[t+128] + gb[t+128]);
  out[orow+t+256] = __float2bfloat16((v2-mean)*rstd*gw[t+256] + gb[t+256]);
}

// ---------------- MFMA GEMM: C = A(bf16,MxK) @ Wb(bf16,NCxK)^T ----------------
// Operand-SWAPPED MFMA + vector epilogue + XCD-bijective swizzle.
// NEW: double-buffered prefetch (T3-minimum: STAGE(next) -> compute(cur) ->
// ONE barrier) so the barrier's vmcnt(0) drain lands after compute; and
// both-sides XOR bank-swizzle (pre-swizzled GLOBAL source + swizzled ds_read,
// rule #21) -> 2 lanes/bank (free) instead of 8/16-way conflicts.
// LDS layout: buf[2] x [128 rows][64 shorts]; stored block8(16B) b at row r
// holds logical block b ^ (r&7).
// EPI 0: qkv scatter (+SCALE on q)   EPI 1: proj + window-reverse + residual(f32) -> bf16
// EPI 2: fc1 + exact gelu -> bf16    EPI 3: fc2 + bias + residual(bf16) -> f32
template<int KD, int EPI>
__global__ __launch_bounds__(256) void k_mgemm(
    const bf16* __restrict__ A, const bf16* __restrict__ Wb,
    const float* __restrict__ bias, const float* __restrict__ aux,
    const bf16* __restrict__ auxb,
    float* __restrict__ outf, bf16* __restrict__ outb, int gx)
{
  __shared__ short As[2][128*64];   // 16 KB each
  __shared__ short Bs[2][128*64];
  int tid  = threadIdx.x;
  int lane = tid & 63, wid = tid >> 6;
  int c15 = lane & 15, h4 = lane >> 4;
  int wr = wid >> 1, wc = wid & 1;

  // XCD-bijective swizzle: XCD j (= bid%8) covers a contiguous tile chunk
  int nwg = gridDim.x, bid = blockIdx.x;
  int swz = (bid & 7) * (nwg >> 3) + (bid >> 3);
  int ty = swz / gx, tx = swz - ty * gx;
  int row0 = ty * 128, col0 = tx * 128;

  f32x4 acc[4][4] = {};          // [n][m]

  // staging: chunk c = wid*4+s covers rows [c*8, c*8+8); lane covers dest
  // block8 (lane&7) of row c*8+(lane>>3); SOURCE block = dest ^ (row&7)
  int srow = lane >> 3;                       // 0..7 within chunk
  int skk  = ((lane & 7) ^ srow) * 8;         // pre-swizzled global k-offset

  const int NT = KD / 64;

  #pragma unroll
  for (int s = 0; s < 4; s++) {               // prologue: stage buf0, k=0
    int c = wid*4 + s;
    ASYNC16(A  + (size_t)(row0 + c*8 + srow)*KD + skk, &As[0][c*512]);
    ASYNC16(Wb + (size_t)(col0 + c*8 + srow)*KD + skk, &Bs[0][c*512]);
  }
  __syncthreads();

  for (int t = 0; t < NT; t++) {
    int cur = t & 1;
    if (t + 1 < NT) {                         // issue next-tile loads first
      int k1 = (t+1)*64;
      #pragma unroll
      for (int s = 0; s < 4; s++) {
        int c = wid*4 + s;
        ASYNC16(A  + (size_t)(row0 + c*8 + srow)*KD + k1 + skk, &As[cur^1][c*512]);
        ASYNC16(Wb + (size_t)(col0 + c*8 + srow)*KD + k1 + skk, &Bs[cur^1][c*512]);
      }
    }
    #pragma unroll
    for (int half = 0; half < 2; half++) {
      bf16x8 af[4], bfr[4];
      int blk8 = ((half << 2) + h4) ^ (c15 & 7);   // swizzled read block
      #pragma unroll
      for (int m = 0; m < 4; m++) {
        int rr = wr*64 + m*16 + c15;
        af[m] = *reinterpret_cast<const bf16x8*>(&As[cur][rr*64 + blk8*8]);
      }
      #pragma unroll
      for (int n = 0; n < 4; n++) {
        int rr = wc*64 + n*16 + c15;
        bfr[n] = *reinterpret_cast<const bf16x8*>(&Bs[cur][rr*64 + blk8*8]);
      }
      #pragma unroll
      for (int n = 0; n < 4; n++)
        #pragma unroll
        for (int m = 0; m < 4; m++)
          acc[n][m] = __builtin_amdgcn_mfma_f32_16x16x32_bf16(bfr[n], af[m], acc[n][m], 0, 0, 0);
    }
    __syncthreads();   // drains next-tile loads (overlapped with compute above)
  }

  // swapped layout: row r = row0+wr*64+m*16+c15 ; col c = col0+wc*64+n*16+h4*4+i
  int rb = row0 + wr*64 + c15;
  int cb = col0 + wc*64 + h4*4;
  #pragma unroll
  for (int m = 0; m < 4; m++) {
    int r = rb + m*16;
    if constexpr (EPI == 0) {
      int b_ = r / NTOK, nn = r % NTOK;
      const size_t QKVSTRIDE = (size_t)BWIN*NHEAD*NTOK*HDHEAD;
      #pragma unroll
      for (int n = 0; n < 4; n++) {
        int c0 = cb + n*16;
        f32x4 v = acc[n][m];
        f32x4 b4 = *(const f32x4*)&bias[c0];
        int which = c0 / CDIM, rem = c0 - which*CDIM;
        int hh = rem >> 5, dd = rem & 31;
        float scl = (which == 0) ? ATTSCALE : 1.f;
        s16x4 o;
        #pragma unroll
        for (int i = 0; i < 4; i++) o[i] = f2bfs((v[i] + b4[i]) * scl);
        *(s16x4*)&outb[(size_t)which*QKVSTRIDE + (((size_t)b_*NHEAD+hh)*NTOK+nn)*HDHEAD + dd] = o;
      }
    } else if constexpr (EPI == 1) {
      int b_ = r / NTOK, nn = r % NTOK;
      int b = b_ >> 4, wi = b_ & 15, wh = wi >> 2, ww = wi & 3;
      int ii = nn / WSZ, jj = nn % WSZ;
      int hh = (wh*WSZ + ii + SSZ) % HDIM;
      int wcc = (ww*WSZ + jj + SSZ) % WDIM;
      size_t rr = ((size_t)b*LDIM + hh*WDIM + wcc) * CDIM;
      #pragma unroll
      for (int n = 0; n < 4; n++) {
        int c0 = cb + n*16;
        f32x4 v = acc[n][m];
        f32x4 b4 = *(const f32x4*)&bias[c0];
        f32x4 a4 = *(const f32x4*)&aux[rr + c0];
        s16x4 o;
        #pragma unroll
        for (int i = 0; i < 4; i++) o[i] = f2bfs(a4[i] + v[i] + b4[i]);
        *(s16x4*)&outb[rr + c0] = o;
      }
    } else if constexpr (EPI == 2) {
      #pragma unroll
      for (int n = 0; n < 4; n++) {
        int c0 = cb + n*16;
        f32x4 v = acc[n][m];
        f32x4 b4 = *(const f32x4*)&bias[c0];
        s16x4 o;
        #pragma unroll
        for (int i = 0; i < 4; i++) {
          float val = v[i] + b4[i];
          val = 0.5f * val * (1.0f + erff(val * 0.70710678118654752f));
          o[i] = f2bfs(val);
        }
        *(s16x4*)&outb[(size_t)r*HIDDIM + c0] = o;
      }
    } else {
      #pragma unroll
      for (int n = 0; n < 4; n++) {
        int c0 = cb + n*16;
        f32x4 v = acc[n][m];
        f32x4 b4 = *(const f32x4*)&bias[c0];
        s16x4 ab = *(const s16x4*)&auxb[(size_t)r*CDIM + c0];
        f32x4 o;
        #pragma unroll
        for (int i = 0; i < 4; i++) o[i] = v[i] + b4[i] + bfs2f(ab[i]);
        *(f32x4*)&outf[(size_t)r*CDIM + c0] = o;
      }
    }
  }
}

// ---------------- MFMA fused window attention ----------------
// barrier-hardened; dummy strip-slots guarded (wave-uniform); no-max softmax
// (scores bounded ~|2|; masked/-1e30 pad underflow to exactly 0)
__global__ __launch_bounds__(256) void k_attn_mfma(const bf16* __restrict__ q,
    const bf16* __restrict__ k, const bf16* __restrict__ v,
    const float* __restrict__ rt, bf16* __restrict__ out)
{
  __shared__ short  Ks[208*KROW];   // [m][k], rows 196..207 zero, padded stride
  __shared__ short  Vt[32*VROW];    // [d][m], cols 196..223 zero, padded stride
  __shared__ short  Ps[4][16*PROW]; // per-wave P strip [row][m], padded stride
  __shared__ float2 tab2[729];      // {bias, rscale} per rel-idx for this head
  __shared__ int    regv[208];

  int blk = blockIdx.x;
  int b_ = blk / NHEAD, head = blk % NHEAD;
  int tid = threadIdx.x, lane = tid & 63, wid = tid >> 6;
  int c15 = lane & 15, h4 = lane >> 4;

  // ---- staging ----
  const bf16* kp = k + (size_t)blk*NTOK*HDHEAD;
  const bf16* vp = v + (size_t)blk*NTOK*HDHEAD;
  for (int c = tid; c < 784; c += 256) {          // 196 rows x 4 chunks of 8
    int m = c >> 2, k8 = (c & 3) * 8;
    *(bf16x8*)&Ks[m*KROW + k8] = *(const bf16x8*)(kp + m*32 + k8);
    bf16x8 vv = *(const bf16x8*)(vp + m*32 + k8);
    #pragma unroll
    for (int j = 0; j < 8; j++) Vt[(k8+j)*VROW + m] = vv[j];
  }
  for (int e = tid; e < 12*KROW; e += 256) Ks[196*KROW + e] = 0;
  for (int e = tid; e < 32*28; e += 256) Vt[(e/28)*VROW + 196 + (e%28)] = 0;
  for (int e = tid; e < 729; e += 256)
    tab2[e] = make_float2(rt[e*2*NHEAD + head], rt[e*2*NHEAD + NHEAD + head]);
  {
    int wi = b_ & 15, wh = wi >> 2, ww = wi & 3;
    for (int e = tid; e < 208; e += 256) {
      int rv = 0;
      if (e < NTOK) {
        int i = e / WSZ, j = e % WSZ;
        int ha = wh*WSZ + i, wa = ww*WSZ + j;
        int rh = ha < (HDIM-WSZ) ? 0 : (ha < (HDIM-SSZ) ? 1 : 2);
        int rw = wa < (WDIM-WSZ) ? 0 : (wa < (WDIM-SSZ) ? 1 : 2);
        rv = rh*3 + rw;
      }
      regv[e] = rv;
    }
  }
  __syncthreads();

  // per-lane m-column constants (m = t*16 + c15)
  int   moff[13], mreg[13];
  float mpad[13];
  #pragma unroll
  for (int t = 0; t < 13; t++) {
    int m  = t*16 + c15;
    int mm = min(m, NTOK-1);
    moff[t] = (mm/WSZ)*27 + (mm%WSZ);
    mreg[t] = regv[mm];
    mpad[t] = (m >= NTOK) ? -1e30f : 0.f;
  }

  short* myP = &Ps[wid][0];
  // zero pad cols 208..223 once (never overwritten: softmax writes cols 0..207)
  #pragma unroll
  for (int i = 0; i < 4; i++) myP[(h4*4+i)*PROW + 208 + c15] = 0;

  bf16* op = out + (size_t)b_*NTOK*CDIM + head*HDHEAD;

  for (int t4 = 0; t4 < 4; t4++) {
    int s = t4*4 + wid;                 // 0..15; 13..15 dummy (guarded off)
    if (s < 13) {
      int qrow = min(s*16 + c15, NTOK-1);
      bf16x8 qf = *(const bf16x8*)(q + ((size_t)blk*NTOK + qrow)*HDHEAD + h4*8);

      f32x4 sc[13];
      #pragma unroll
      for (int t = 0; t < 13; t++) {
        bf16x8 kf = *(const bf16x8*)&Ks[(t*16 + c15)*KROW + h4*8];
        sc[t] = __builtin_amdgcn_mfma_f32_16x16x32_bf16(qf, kf, (f32x4){0.f,0.f,0.f,0.f}, 0, 0, 0);
      }

      #pragma unroll
      for (int i = 0; i < 4; i++) {
        int n  = s*16 + h4*4 + i;
        int nc = min(n, NTOK-1);
        int nbase = ((nc/WSZ) + 13)*27 + (nc%WSZ) + 13;
        int nreg  = regv[nc];
        float rr[13];
        float sum = 0.f;
        #pragma unroll
        for (int t = 0; t < 13; t++) {
          float2 hr = tab2[nbase - moff[t]];
          float sv = sc[t][i] + hr.x + ((mreg[t] != nreg) ? -100.f : 0.f) + mpad[t];
          float e = __expf(sv);          // no-max softmax: |sv| tiny or -> 0
          rr[t] = hr.y;
          sc[t][i] = e; sum += e;
        }
        #pragma unroll
        for (int o = 1; o < 16; o <<= 1) sum += __shfl_xor(sum, o);
        float inv = 1.f / sum;
        int prow = h4*4 + i;
        #pragma unroll
        for (int t = 0; t < 13; t++)
          myP[prow*PROW + t*16 + c15] = f2bfs(sc[t][i] * inv * rr[t]);  // short store
      }
    }

    __syncthreads();   // drain P ds_writes before PV ds_reads (all waves uniform)

    if (s < 13) {
      // PV: O[16 x 32] = P[16 x 224] @ Vt^T
      f32x4 o0 = {0.f,0.f,0.f,0.f}, o1 = {0.f,0.f,0.f,0.f};
      #pragma unroll
      for (int t7 = 0; t7 < 7; t7++) {
        bf16x8 pf = *(const bf16x8*)&myP[c15*PROW + t7*32 + h4*8];
        bf16x8 v0 = *(const bf16x8*)&Vt[c15*VROW + t7*32 + h4*8];
        bf16x8 v1 = *(const bf16x8*)&Vt[(16 + c15)*VROW + t7*32 + h4*8];
        o0 = __builtin_amdgcn_mfma_f32_16x16x32_bf16(pf, v0, o0, 0, 0, 0);
        o1 = __builtin_amdgcn_mfma_f32_16x16x32_bf16(pf, v1, o1, 0, 0, 0);
      }

      #pragma unroll
      for (int i = 0; i < 4; i++) {
        int n = s*16 + h4*4 + i;
        if (n < NTOK) {
          op[(size_t)n*CDIM + c15]      = __float2bfloat16(o0[i]);
          op[(size_t)n*CDIM + 16 + c15] = __float2bfloat16(o1[i]);
        }
      }
    }

    __syncthreads();   // PV reads done before next strip's P writes
  }
}

// ---------------- launch ----------------
extern "C" void kernel_launch(void* const* d_in, const int* in_sizes, int n_in,
                              void* d_out, int out_size, void* d_ws, size_t ws_size,
                              hipStream_t stream)
{
  const float* x      = (const float*)d_in[0];
  const float* n1w    = (const float*)d_in[1];
  const float* n1b    = (const float*)d_in[2];
  const float* qkv_w  = (const float*)d_in[3];
  const float* qkv_b  = (const float*)d_in[4];
  const float* proj_w = (const float*)d_in[5];
  const float* proj_b = (const float*)d_in[6];
  const float* rt     = (const float*)d_in[7];
  const float* n2w    = (const float*)d_in[8];
  const float* n2b    = (const float*)d_in[9];
  const float* fc1_w  = (const float*)d_in[10];
  const float* fc1_b  = (const float*)d_in[11];
  const float* fc2_w  = (const float*)d_in[12];
  const float* fc2_b  = (const float*)d_in[13];

  char* ws = (char*)d_ws;
  const size_t SZ_BF = (size_t)MROWS * CDIM * 2;   // 77,070,336 B
  // arena (total exactly 8*SZ_BF, proven footprint):
  //  R0 [0,1SZ):    xw -> attnout -> (after proj) wf1,wf2
  //  R1 [1SZ,4SZ):  qkv -> x2(bf16,[1SZ,2SZ)) + hln([2SZ,3SZ))
  //  R2 [4SZ,8SZ):  wq,wp (head) -> hid (overwrites dead wq/wp at fc1)
  bf16*  xw      = (bf16*)ws;
  bf16*  attnout = (bf16*)ws;
  bf16*  qkv     = (bf16*)(ws + SZ_BF);
  bf16*  x2b     = (bf16*)(ws + SZ_BF);
  bf16*  hln     = (bf16*)(ws + 2*SZ_BF);
  bf16*  hid     = (bf16*)(ws + 4*SZ_BF);
  const int NQKVW = 3*CDIM*CDIM;      // 442368
  const int NPROJW = CDIM*CDIM;       // 147456
  const int NFCW  = HIDDIM*CDIM;      // 589824
  bf16* wq  = (bf16*)(ws + 4*SZ_BF);  // lives in R2 until fc1 clobbers it
  bf16* wp  = wq + NQKVW;
  bf16* wf1 = (bf16*)ws;              // converted into R0 after proj GEMM
  bf16* wf2 = wf1 + NFCW;
  const size_t QKVSTRIDE = (size_t)BWIN*NHEAD*NTOK*HDHEAD;

  k_cvt<<<(NQKVW+255)/256, 256, 0, stream>>>(qkv_w, wq, NQKVW);
  k_cvt<<<(NPROJW+255)/256, 256, 0, stream>>>(proj_w, wp, NPROJW);

  k_ln<true, float><<<MROWS, 128, 0, stream>>>(x, n1w, n1b, xw);
  k_mgemm<CDIM, 0><<<9*(MROWS/128), 256, 0, stream>>>(
      xw, wq, qkv_b, nullptr, nullptr, nullptr, qkv, 9);
  k_attn_mfma<<<BWIN*NHEAD, 256, 0, stream>>>(
      qkv, qkv + QKVSTRIDE, qkv + 2*QKVSTRIDE, rt, attnout);
  k_mgemm<CDIM, 1><<<3*(MROWS/128), 256, 0, stream>>>(
      attnout, wp, proj_b, x, nullptr, nullptr, x2b, 3);

  k_cvt<<<(NFCW+255)/256, 256, 0, stream>>>(fc1_w, wf1, NFCW);
  k_cvt<<<(NFCW+255)/256, 256, 0, stream>>>(fc2_w, wf2, NFCW);

  k_ln<false, bf16><<<MROWS, 128, 0, stream>>>(x2b, n2w, n2b, hln);
  k_mgemm<CDIM, 2><<<12*(MROWS/128), 256, 0, stream>>>(
      hln, wf1, fc1_b, nullptr, nullptr, nullptr, hid, 12);
  k_mgemm<HIDDIM, 3><<<3*(MROWS/128), 256, 0, stream>>>(
      hid, wf2, fc2_b, nullptr, x2b, (float*)d_out, nullptr, 3);
}

// Round 10
// 1042.806 us; speedup vs baseline: 1.0700x; 1.0700x over previous
//
#include <hip/hip_runtime.h>
#include <hip/hip_bf16.h>
#include <math.h>

// ---------------- problem constants ----------------
#define BDIM 32
#define HDIM 56
#define WDIM 56
#define CDIM 384
#define NHEAD 12
#define WSZ 14
#define SSZ 7
#define LDIM (HDIM*WDIM)        // 3136
#define NTOK (WSZ*WSZ)          // 196
#define HDHEAD (CDIM/NHEAD)     // 32
#define HIDDIM (4*CDIM)         // 1536
#define NWIN 16
#define BWIN (BDIM*NWIN)        // 512
#define MROWS (BDIM*LDIM)       // 100352 == BWIN*NTOK
#define EPSLN 1e-5f
#define ATTSCALE 0.17677669529663687f   // 32^-0.5
#define QKVC (3*CDIM)           // 1152, contiguous qkv row stride

// padded LDS strides (shorts) for attention
#define KROW 40
#define VROW 232
#define PROW 232

typedef __hip_bfloat16 bf16;
typedef __attribute__((ext_vector_type(8))) short bf16x8;   // 8 bf16 = 4 VGPRs
typedef __attribute__((ext_vector_type(4))) short s16x4;    // 4 bf16 = 1 b64 store
typedef __attribute__((ext_vector_type(4))) float f32x4;

// async global->LDS, 16B per lane, wave-uniform LDS base
#define ASYNC16(gp, lp) __builtin_amdgcn_global_load_lds( \
    (__attribute__((address_space(1))) void*)(gp),        \
    (__attribute__((address_space(3))) void*)(lp), 16, 0, 0)

// float -> bf16 bit pattern as short (type-consistent with short LDS arrays)
static __device__ __forceinline__ short f2bfs(float x) {
  union { bf16 h; short s; } u; u.h = __float2bfloat16(x); return u.s;
}
static __device__ __forceinline__ float bfs2f(short s) {
  unsigned int u = ((unsigned int)(unsigned short)s) << 16;
  float f; __builtin_memcpy(&f, &u, 4); return f;
}
static __device__ __forceinline__ float tof(float x) { return x; }
static __device__ __forceinline__ float tof(bf16 x)  { return __bfloat162float(x); }

// ---------------- fp32 -> bf16 weight convert ----------------
__global__ __launch_bounds__(256) void k_cvt(const float* __restrict__ in,
                                             bf16* __restrict__ out, int n)
{
  int i = blockIdx.x * 256 + threadIdx.x;
  if (i < n) out[i] = __float2bfloat16(in[i]);
}

// ---------------- LN (+optional shift-roll + window partition) ----------------
template<bool WIN, typename TIN>
__global__ __launch_bounds__(128) void k_ln(const TIN* __restrict__ xin,
    const float* __restrict__ gw, const float* __restrict__ gb,
    bf16* __restrict__ out)
{
  int r = blockIdx.x;
  int t = threadIdx.x;
  const TIN* xp = xin + (size_t)r * CDIM;
  float v0 = tof(xp[t]), v1 = tof(xp[t+128]), v2 = tof(xp[t+256]);
  float s  = v0+v1+v2;
  float ss = v0*v0 + v1*v1 + v2*v2;
  #pragma unroll
  for (int o = 32; o > 0; o >>= 1) { s += __shfl_down(s, o); ss += __shfl_down(ss, o); }
  __shared__ float red[4];
  if ((t & 63) == 0) { red[(t>>6)*2] = s; red[(t>>6)*2+1] = ss; }
  __syncthreads();
  float mean = (red[0]+red[2]) * (1.0f/CDIM);
  float var  = (red[1]+red[3]) * (1.0f/CDIM) - mean*mean;
  float rstd = rsqrtf(var + EPSLN);

  size_t orow;
  if (WIN) {
    int b = r / LDIM, l = r % LDIM;
    int h = l / WDIM, w = l % WDIM;
    int h2 = (h + HDIM - SSZ) % HDIM, w2 = (w + WDIM - SSZ) % WDIM;
    int wh = h2 / WSZ, ii = h2 % WSZ, ww = w2 / WSZ, jj = w2 % WSZ;
    int b_ = b*NWIN + wh*4 + ww;
    int n  = ii*WSZ + jj;
    orow = ((size_t)b_*NTOK + n) * CDIM;
  } else {
    orow = (size_t)r * CDIM;
  }
  out[orow+t]     = __float2bfloat16((v0-mean)*rstd*gw[t]     + gb[t]);
  out[orow+t+128] = __float2bfloat16((v1-mean)*rstd*gw[t+128] + gb[t+128]);
  out[orow+t+256] = __float2bfloat16((v2-mean)*rstd*gw[t+256] + gb[t+256]);
}

// ---------------- MFMA GEMM: C = A(bf16,MxK) @ Wb(bf16,NCxK)^T ----------------
// 256x128 tile, 512 threads (8 waves = 4M x 2N), BK=64, single 48KB LDS buffer.
// Operand-SWAPPED MFMA (lane owns row + 4 consecutive cols) + vector epilogue.
// Both-sides XOR bank-swizzle (pre-swizzled global src + swizzled ds_read).
// XCD-bijective 1-D grid swizzle (nwg % 8 == 0).
// EPI 0: qkv contiguous [r][1152] (+SCALE on q cols)
// EPI 1: proj + window-reverse + residual(f32) -> bf16
// EPI 2: fc1 + exact gelu -> bf16    EPI 3: fc2 + bias + residual(bf16) -> f32
template<int KD, int EPI>
__global__ __launch_bounds__(512, 4) void k_mgemm(
    const bf16* __restrict__ A, const bf16* __restrict__ Wb,
    const float* __restrict__ bias, const float* __restrict__ aux,
    const bf16* __restrict__ auxb,
    float* __restrict__ outf, bf16* __restrict__ outb, int gx)
{
  __shared__ short As[256*64];   // 32 KB
  __shared__ short Bs[128*64];   // 16 KB
  int tid  = threadIdx.x;
  int lane = tid & 63, wid = tid >> 6;
  int c15 = lane & 15, h4 = lane >> 4;
  int wr = wid >> 1, wc = wid & 1;          // 4 M-quarters x 2 N-halves

  // XCD-bijective swizzle: XCD j (= bid%8) covers a contiguous tile chunk
  int nwg = gridDim.x, bid = blockIdx.x;
  int swz = (bid & 7) * (nwg >> 3) + (bid >> 3);
  int ty = swz / gx, tx = swz - ty * gx;
  int row0 = ty * 256, col0 = tx * 128;

  f32x4 acc[4][4] = {};          // [n][m]

  // staging: chunk c covers rows [c*8, c*8+8); lane -> dest block8 (lane&7)
  // of row (lane>>3); SOURCE logical block = dest ^ row  (both-sides swizzle)
  int srow = lane >> 3;                       // 0..7 within chunk
  int skk  = ((lane & 7) ^ srow) * 8;         // pre-swizzled global k-offset

  const int NT = KD / 64;

  for (int t = 0; t < NT; t++) {
    int k0 = t * 64;
    #pragma unroll
    for (int s = 0; s < 4; s++) {             // A: 32 chunks, 4 per wave
      int c = wid*4 + s;
      ASYNC16(A + (size_t)(row0 + c*8 + srow)*KD + k0 + skk, &As[c*512]);
    }
    #pragma unroll
    for (int s = 0; s < 2; s++) {             // B: 16 chunks, 2 per wave
      int c = wid*2 + s;
      ASYNC16(Wb + (size_t)(col0 + c*8 + srow)*KD + k0 + skk, &Bs[c*512]);
    }
    __syncthreads();

    #pragma unroll
    for (int half = 0; half < 2; half++) {
      bf16x8 af[4], bfr[4];
      int blk8 = ((half << 2) + h4) ^ (c15 & 7);   // swizzled read block
      #pragma unroll
      for (int m = 0; m < 4; m++) {
        int rr = wr*64 + m*16 + c15;
        af[m] = *reinterpret_cast<const bf16x8*>(&As[rr*64 + blk8*8]);
      }
      #pragma unroll
      for (int n = 0; n < 4; n++) {
        int rr = wc*64 + n*16 + c15;
        bfr[n] = *reinterpret_cast<const bf16x8*>(&Bs[rr*64 + blk8*8]);
      }
      #pragma unroll
      for (int n = 0; n < 4; n++)
        #pragma unroll
        for (int m = 0; m < 4; m++)
          acc[n][m] = __builtin_amdgcn_mfma_f32_16x16x32_bf16(bfr[n], af[m], acc[n][m], 0, 0, 0);
    }
    __syncthreads();
  }

  // swapped layout: row r = row0+wr*64+m*16+c15 ; col c = col0+wc*64+n*16+h4*4+i
  int rb = row0 + wr*64 + c15;
  int cb = col0 + wc*64 + h4*4;
  #pragma unroll
  for (int m = 0; m < 4; m++) {
    int r = rb + m*16;
    if constexpr (EPI == 0) {
      #pragma unroll
      for (int n = 0; n < 4; n++) {
        int c0 = cb + n*16;
        f32x4 v = acc[n][m];
        f32x4 b4 = *(const f32x4*)&bias[c0];
        float scl = (c0 < CDIM) ? ATTSCALE : 1.f;
        s16x4 o;
        #pragma unroll
        for (int i = 0; i < 4; i++) o[i] = f2bfs((v[i] + b4[i]) * scl);
        *(s16x4*)&outb[(size_t)r*QKVC + c0] = o;
      }
    } else if constexpr (EPI == 1) {
      int b_ = r / NTOK, nn = r % NTOK;
      int b = b_ >> 4, wi = b_ & 15, wh = wi >> 2, ww = wi & 3;
      int ii = nn / WSZ, jj = nn % WSZ;
      int hh = (wh*WSZ + ii + SSZ) % HDIM;
      int wcc = (ww*WSZ + jj + SSZ) % WDIM;
      size_t rr = ((size_t)b*LDIM + hh*WDIM + wcc) * CDIM;
      #pragma unroll
      for (int n = 0; n < 4; n++) {
        int c0 = cb + n*16;
        f32x4 v = acc[n][m];
        f32x4 b4 = *(const f32x4*)&bias[c0];
        f32x4 a4 = *(const f32x4*)&aux[rr + c0];
        s16x4 o;
        #pragma unroll
        for (int i = 0; i < 4; i++) o[i] = f2bfs(a4[i] + v[i] + b4[i]);
        *(s16x4*)&outb[rr + c0] = o;
      }
    } else if constexpr (EPI == 2) {
      #pragma unroll
      for (int n = 0; n < 4; n++) {
        int c0 = cb + n*16;
        f32x4 v = acc[n][m];
        f32x4 b4 = *(const f32x4*)&bias[c0];
        s16x4 o;
        #pragma unroll
        for (int i = 0; i < 4; i++) {
          float val = v[i] + b4[i];
          val = 0.5f * val * (1.0f + erff(val * 0.70710678118654752f));
          o[i] = f2bfs(val);
        }
        *(s16x4*)&outb[(size_t)r*HIDDIM + c0] = o;
      }
    } else {
      #pragma unroll
      for (int n = 0; n < 4; n++) {
        int c0 = cb + n*16;
        f32x4 v = acc[n][m];
        f32x4 b4 = *(const f32x4*)&bias[c0];
        s16x4 ab = *(const s16x4*)&auxb[(size_t)r*CDIM + c0];
        f32x4 o;
        #pragma unroll
        for (int i = 0; i < 4; i++) o[i] = v[i] + b4[i] + bfs2f(ab[i]);
        *(f32x4*)&outf[(size_t)r*CDIM + c0] = o;
      }
    }
  }
}

// ---------------- MFMA fused window attention ----------------
// barrier-hardened; dummy strip-slots guarded (wave-uniform); no-max softmax.
// qkv input is contiguous [row][1152]: q cols [0,384), k [384,768), v [768,1152).
__global__ __launch_bounds__(256) void k_attn_mfma(const bf16* __restrict__ qkv,
    const float* __restrict__ rt, bf16* __restrict__ out)
{
  __shared__ short  Ks[208*KROW];   // [m][k], rows 196..207 zero, padded stride
  __shared__ short  Vt[32*VROW];    // [d][m], cols 196..223 zero, padded stride
  __shared__ short  Ps[4][16*PROW]; // per-wave P strip [row][m], padded stride
  __shared__ float2 tab2[729];      // {bias, rscale} per rel-idx for this head
  __shared__ int    regv[208];

  int blk = blockIdx.x;
  int b_ = blk / NHEAD, head = blk % NHEAD;
  int tid = threadIdx.x, lane = tid & 63, wid = tid >> 6;
  int c15 = lane & 15, h4 = lane >> 4;

  // ---- staging ----
  const bf16* rowbase = qkv + (size_t)b_*NTOK*QKVC + head*HDHEAD;
  const bf16* kp = rowbase + CDIM;      // k block
  const bf16* vp = rowbase + 2*CDIM;    // v block
  for (int c = tid; c < 784; c += 256) {          // 196 rows x 4 chunks of 8
    int m = c >> 2, k8 = (c & 3) * 8;
    *(bf16x8*)&Ks[m*KROW + k8] = *(const bf16x8*)(kp + (size_t)m*QKVC + k8);
    bf16x8 vv = *(const bf16x8*)(vp + (size_t)m*QKVC + k8);
    #pragma unroll
    for (int j = 0; j < 8; j++) Vt[(k8+j)*VROW + m] = vv[j];
  }
  for (int e = tid; e < 12*KROW; e += 256) Ks[196*KROW + e] = 0;
  for (int e = tid; e < 32*28; e += 256) Vt[(e/28)*VROW + 196 + (e%28)] = 0;
  for (int e = tid; e < 729; e += 256)
    tab2[e] = make_float2(rt[e*2*NHEAD + head], rt[e*2*NHEAD + NHEAD + head]);
  {
    int wi = b_ & 15, wh = wi >> 2, ww = wi & 3;
    for (int e = tid; e < 208; e += 256) {
      int rv = 0;
      if (e < NTOK) {
        int i = e / WSZ, j = e % WSZ;
        int ha = wh*WSZ + i, wa = ww*WSZ + j;
        int rh = ha < (HDIM-WSZ) ? 0 : (ha < (HDIM-SSZ) ? 1 : 2);
        int rw = wa < (WDIM-WSZ) ? 0 : (wa < (WDIM-SSZ) ? 1 : 2);
        rv = rh*3 + rw;
      }
      regv[e] = rv;
    }
  }
  __syncthreads();

  // per-lane m-column constants (m = t*16 + c15)
  int   moff[13], mreg[13];
  float mpad[13];
  #pragma unroll
  for (int t = 0; t < 13; t++) {
    int m  = t*16 + c15;
    int mm = min(m, NTOK-1);
    moff[t] = (mm/WSZ)*27 + (mm%WSZ);
    mreg[t] = regv[mm];
    mpad[t] = (m >= NTOK) ? -1e30f : 0.f;
  }

  short* myP = &Ps[wid][0];
  // zero pad cols 208..223 once (never overwritten: softmax writes cols 0..207)
  #pragma unroll
  for (int i = 0; i < 4; i++) myP[(h4*4+i)*PROW + 208 + c15] = 0;

  bf16* op = out + (size_t)b_*NTOK*CDIM + head*HDHEAD;

  for (int t4 = 0; t4 < 4; t4++) {
    int s = t4*4 + wid;                 // 0..15; 13..15 dummy (guarded off)
    if (s < 13) {
      int qrow = min(s*16 + c15, NTOK-1);
      bf16x8 qf = *(const bf16x8*)(rowbase + (size_t)qrow*QKVC + h4*8);

      f32x4 sc[13];
      #pragma unroll
      for (int t = 0; t < 13; t++) {
        bf16x8 kf = *(const bf16x8*)&Ks[(t*16 + c15)*KROW + h4*8];
        sc[t] = __builtin_amdgcn_mfma_f32_16x16x32_bf16(qf, kf, (f32x4){0.f,0.f,0.f,0.f}, 0, 0, 0);
      }

      #pragma unroll
      for (int i = 0; i < 4; i++) {
        int n  = s*16 + h4*4 + i;
        int nc = min(n, NTOK-1);
        int nbase = ((nc/WSZ) + 13)*27 + (nc%WSZ) + 13;
        int nreg  = regv[nc];
        float rr[13];
        float sum = 0.f;
        #pragma unroll
        for (int t = 0; t < 13; t++) {
          float2 hr = tab2[nbase - moff[t]];
          float sv = sc[t][i] + hr.x + ((mreg[t] != nreg) ? -100.f : 0.f) + mpad[t];
          float e = __expf(sv);          // no-max softmax: |sv| tiny or -> 0
          rr[t] = hr.y;
          sc[t][i] = e; sum += e;
        }
        #pragma unroll
        for (int o = 1; o < 16; o <<= 1) sum += __shfl_xor(sum, o);
        float inv = 1.f / sum;
        int prow = h4*4 + i;
        #pragma unroll
        for (int t = 0; t < 13; t++)
          myP[prow*PROW + t*16 + c15] = f2bfs(sc[t][i] * inv * rr[t]);  // short store
      }
    }

    __syncthreads();   // drain P ds_writes before PV ds_reads (all waves uniform)

    if (s < 13) {
      // PV: O[16 x 32] = P[16 x 224] @ Vt^T
      f32x4 o0 = {0.f,0.f,0.f,0.f}, o1 = {0.f,0.f,0.f,0.f};
      #pragma unroll
      for (int t7 = 0; t7 < 7; t7++) {
        bf16x8 pf = *(const bf16x8*)&myP[c15*PROW + t7*32 + h4*8];
        bf16x8 v0 = *(const bf16x8*)&Vt[c15*VROW + t7*32 + h4*8];
        bf16x8 v1 = *(const bf16x8*)&Vt[(16 + c15)*VROW + t7*32 + h4*8];
        o0 = __builtin_amdgcn_mfma_f32_16x16x32_bf16(pf, v0, o0, 0, 0, 0);
        o1 = __builtin_amdgcn_mfma_f32_16x16x32_bf16(pf, v1, o1, 0, 0, 0);
      }

      #pragma unroll
      for (int i = 0; i < 4; i++) {
        int n = s*16 + h4*4 + i;
        if (n < NTOK) {
          op[(size_t)n*CDIM + c15]      = __float2bfloat16(o0[i]);
          op[(size_t)n*CDIM + 16 + c15] = __float2bfloat16(o1[i]);
        }
      }
    }

    __syncthreads();   // PV reads done before next strip's P writes
  }
}

// ---------------- launch ----------------
extern "C" void kernel_launch(void* const* d_in, const int* in_sizes, int n_in,
                              void* d_out, int out_size, void* d_ws, size_t ws_size,
                              hipStream_t stream)
{
  const float* x      = (const float*)d_in[0];
  const float* n1w    = (const float*)d_in[1];
  const float* n1b    = (const float*)d_in[2];
  const float* qkv_w  = (const float*)d_in[3];
  const float* qkv_b  = (const float*)d_in[4];
  const float* proj_w = (const float*)d_in[5];
  const float* proj_b = (const float*)d_in[6];
  const float* rt     = (const float*)d_in[7];
  const float* n2w    = (const float*)d_in[8];
  const float* n2b    = (const float*)d_in[9];
  const float* fc1_w  = (const float*)d_in[10];
  const float* fc1_b  = (const float*)d_in[11];
  const float* fc2_w  = (const float*)d_in[12];
  const float* fc2_b  = (const float*)d_in[13];

  char* ws = (char*)d_ws;
  const size_t SZ_BF = (size_t)MROWS * CDIM * 2;   // 77,070,336 B
  // arena (total exactly 8*SZ_BF, proven footprint):
  //  R0 [0,1SZ):    xw -> attnout -> (after proj) wf1,wf2
  //  R1 [1SZ,4SZ):  qkv (contiguous [r][1152]) -> x2(bf16,[1SZ,2SZ)) + hln([2SZ,3SZ))
  //  R2 [4SZ,8SZ):  wq,wp (head) -> hid (overwrites dead wq/wp at fc1)
  bf16*  xw      = (bf16*)ws;
  bf16*  attnout = (bf16*)ws;
  bf16*  qkv     = (bf16*)(ws + SZ_BF);
  bf16*  x2b     = (bf16*)(ws + SZ_BF);
  bf16*  hln     = (bf16*)(ws + 2*SZ_BF);
  bf16*  hid     = (bf16*)(ws + 4*SZ_BF);
  const int NQKVW = 3*CDIM*CDIM;      // 442368
  const int NPROJW = CDIM*CDIM;       // 147456
  const int NFCW  = HIDDIM*CDIM;      // 589824
  bf16* wq  = (bf16*)(ws + 4*SZ_BF);  // lives in R2 until fc1 clobbers it
  bf16* wp  = wq + NQKVW;
  bf16* wf1 = (bf16*)ws;              // converted into R0 after proj GEMM
  bf16* wf2 = wf1 + NFCW;

  k_cvt<<<(NQKVW+255)/256, 256, 0, stream>>>(qkv_w, wq, NQKVW);
  k_cvt<<<(NPROJW+255)/256, 256, 0, stream>>>(proj_w, wp, NPROJW);

  k_ln<true, float><<<MROWS, 128, 0, stream>>>(x, n1w, n1b, xw);
  k_mgemm<CDIM, 0><<<(MROWS/256)*9, 512, 0, stream>>>(
      xw, wq, qkv_b, nullptr, nullptr, nullptr, qkv, 9);
  k_attn_mfma<<<BWIN*NHEAD, 256, 0, stream>>>(qkv, rt, attnout);
  k_mgemm<CDIM, 1><<<(MROWS/256)*3, 512, 0, stream>>>(
      attnout, wp, proj_b, x, nullptr, nullptr, x2b, 3);

  k_cvt<<<(NFCW+255)/256, 256, 0, stream>>>(fc1_w, wf1, NFCW);
  k_cvt<<<(NFCW+255)/256, 256, 0, stream>>>(fc2_w, wf2, NFCW);

  k_ln<false, bf16><<<MROWS, 128, 0, stream>>>(x2b, n2w, n2b, hln);
  k_mgemm<CDIM, 2><<<(MROWS/256)*12, 512, 0, stream>>>(
      hln, wf1, fc1_b, nullptr, nullptr, nullptr, hid, 12);
  k_mgemm<HIDDIM, 3><<<(MROWS/256)*3, 512, 0, stream>>>(
      hid, wf2, fc2_b, nullptr, x2b, (float*)d_out, nullptr, 3);
}

// Round 11
// 1035.137 us; speedup vs baseline: 1.0779x; 1.0074x over previous
//
#include <hip/hip_runtime.h>
#include <hip/hip_bf16.h>
#include <math.h>

// ---------------- problem constants ----------------
#define BDIM 32
#define HDIM 56
#define WDIM 56
#define CDIM 384
#define NHEAD 12
#define WSZ 14
#define SSZ 7
#define LDIM (HDIM*WDIM)        // 3136
#define NTOK (WSZ*WSZ)          // 196
#define HDHEAD (CDIM/NHEAD)     // 32
#define HIDDIM (4*CDIM)         // 1536
#define NWIN 16
#define BWIN (BDIM*NWIN)        // 512
#define MROWS (BDIM*LDIM)       // 100352 == BWIN*NTOK
#define EPSLN 1e-5f
#define ATTSCALE 0.17677669529663687f   // 32^-0.5
#define QKVC (3*CDIM)           // 1152, contiguous qkv row stride

// padded LDS strides (shorts) for attention
#define KROW 40
#define VROW 232
#define PROW 232

typedef __hip_bfloat16 bf16;
typedef __attribute__((ext_vector_type(8))) short bf16x8;   // 8 bf16 = 4 VGPRs
typedef __attribute__((ext_vector_type(4))) short s16x4;    // 4 bf16 = 1 b64 store
typedef __attribute__((ext_vector_type(4))) float f32x4;

// async global->LDS, 16B per lane, wave-uniform LDS base
#define ASYNC16(gp, lp) __builtin_amdgcn_global_load_lds( \
    (__attribute__((address_space(1))) void*)(gp),        \
    (__attribute__((address_space(3))) void*)(lp), 16, 0, 0)

// float -> bf16 bit pattern as short (type-consistent with short LDS arrays)
static __device__ __forceinline__ short f2bfs(float x) {
  union { bf16 h; short s; } u; u.h = __float2bfloat16(x); return u.s;
}
static __device__ __forceinline__ float bfs2f(short s) {
  unsigned int u = ((unsigned int)(unsigned short)s) << 16;
  float f; __builtin_memcpy(&f, &u, 4); return f;
}
static __device__ __forceinline__ float tof(float x) { return x; }
static __device__ __forceinline__ float tof(bf16 x)  { return __bfloat162float(x); }

// ---------------- fp32 -> bf16 weight convert ----------------
__global__ __launch_bounds__(256) void k_cvt(const float* __restrict__ in,
                                             bf16* __restrict__ out, int n)
{
  int i = blockIdx.x * 256 + threadIdx.x;
  if (i < n) out[i] = __float2bfloat16(in[i]);
}

// ---------------- LN (+optional shift-roll + window partition) ----------------
template<bool WIN, typename TIN>
__global__ __launch_bounds__(128) void k_ln(const TIN* __restrict__ xin,
    const float* __restrict__ gw, const float* __restrict__ gb,
    bf16* __restrict__ out)
{
  int r = blockIdx.x;
  int t = threadIdx.x;
  const TIN* xp = xin + (size_t)r * CDIM;
  float v0 = tof(xp[t]), v1 = tof(xp[t+128]), v2 = tof(xp[t+256]);
  float s  = v0+v1+v2;
  float ss = v0*v0 + v1*v1 + v2*v2;
  #pragma unroll
  for (int o = 32; o > 0; o >>= 1) { s += __shfl_down(s, o); ss += __shfl_down(ss, o); }
  __shared__ float red[4];
  if ((t & 63) == 0) { red[(t>>6)*2] = s; red[(t>>6)*2+1] = ss; }
  __syncthreads();
  float mean = (red[0]+red[2]) * (1.0f/CDIM);
  float var  = (red[1]+red[3]) * (1.0f/CDIM) - mean*mean;
  float rstd = rsqrtf(var + EPSLN);

  size_t orow;
  if (WIN) {
    int b = r / LDIM, l = r % LDIM;
    int h = l / WDIM, w = l % WDIM;
    int h2 = (h + HDIM - SSZ) % HDIM, w2 = (w + WDIM - SSZ) % WDIM;
    int wh = h2 / WSZ, ii = h2 % WSZ, ww = w2 / WSZ, jj = w2 % WSZ;
    int b_ = b*NWIN + wh*4 + ww;
    int n  = ii*WSZ + jj;
    orow = ((size_t)b_*NTOK + n) * CDIM;
  } else {
    orow = (size_t)r * CDIM;
  }
  out[orow+t]     = __float2bfloat16((v0-mean)*rstd*gw[t]     + gb[t]);
  out[orow+t+128] = __float2bfloat16((v1-mean)*rstd*gw[t+128] + gb[t+128]);
  out[orow+t+256] = __float2bfloat16((v2-mean)*rstd*gw[t+256] + gb[t+256]);
}

// ---------------- MFMA GEMM: C = A(bf16,MxK) @ Wb(bf16,NCxK)^T ----------------
// 256x128 tile, 512 threads (8 waves = 4M x 2N), BK=64, single 48KB LDS buffer.
// Operand-SWAPPED MFMA (lane owns row + 4 consecutive cols) + vector epilogue.
// Both-sides XOR bank-swizzle (pre-swizzled global src + swizzled ds_read).
// XCD-bijective 1-D grid swizzle (nwg % 8 == 0).
// EPI 0: qkv contiguous [r][1152] (+SCALE on q cols)
// EPI 1: proj + window-reverse + residual(f32) -> bf16
// EPI 2: fc1 + exact gelu -> bf16    EPI 3: fc2 + bias + residual(bf16) -> f32
template<int KD, int EPI>
__global__ __launch_bounds__(512, 4) void k_mgemm(
    const bf16* __restrict__ A, const bf16* __restrict__ Wb,
    const float* __restrict__ bias, const float* __restrict__ aux,
    const bf16* __restrict__ auxb,
    float* __restrict__ outf, bf16* __restrict__ outb, int gx)
{
  __shared__ short As[256*64];   // 32 KB
  __shared__ short Bs[128*64];   // 16 KB
  int tid  = threadIdx.x;
  int lane = tid & 63, wid = tid >> 6;
  int c15 = lane & 15, h4 = lane >> 4;
  int wr = wid >> 1, wc = wid & 1;          // 4 M-quarters x 2 N-halves

  // XCD-bijective swizzle: XCD j (= bid%8) covers a contiguous tile chunk
  int nwg = gridDim.x, bid = blockIdx.x;
  int swz = (bid & 7) * (nwg >> 3) + (bid >> 3);
  int ty = swz / gx, tx = swz - ty * gx;
  int row0 = ty * 256, col0 = tx * 128;

  f32x4 acc[4][4] = {};          // [n][m]

  // staging: chunk c covers rows [c*8, c*8+8); lane -> dest block8 (lane&7)
  // of row (lane>>3); SOURCE logical block = dest ^ row  (both-sides swizzle)
  int srow = lane >> 3;                       // 0..7 within chunk
  int skk  = ((lane & 7) ^ srow) * 8;         // pre-swizzled global k-offset

  const int NT = KD / 64;

  for (int t = 0; t < NT; t++) {
    int k0 = t * 64;
    #pragma unroll
    for (int s = 0; s < 4; s++) {             // A: 32 chunks, 4 per wave
      int c = wid*4 + s;
      ASYNC16(A + (size_t)(row0 + c*8 + srow)*KD + k0 + skk, &As[c*512]);
    }
    #pragma unroll
    for (int s = 0; s < 2; s++) {             // B: 16 chunks, 2 per wave
      int c = wid*2 + s;
      ASYNC16(Wb + (size_t)(col0 + c*8 + srow)*KD + k0 + skk, &Bs[c*512]);
    }
    __syncthreads();

    #pragma unroll
    for (int half = 0; half < 2; half++) {
      bf16x8 af[4], bfr[4];
      int blk8 = ((half << 2) + h4) ^ (c15 & 7);   // swizzled read block
      #pragma unroll
      for (int m = 0; m < 4; m++) {
        int rr = wr*64 + m*16 + c15;
        af[m] = *reinterpret_cast<const bf16x8*>(&As[rr*64 + blk8*8]);
      }
      #pragma unroll
      for (int n = 0; n < 4; n++) {
        int rr = wc*64 + n*16 + c15;
        bfr[n] = *reinterpret_cast<const bf16x8*>(&Bs[rr*64 + blk8*8]);
      }
      #pragma unroll
      for (int n = 0; n < 4; n++)
        #pragma unroll
        for (int m = 0; m < 4; m++)
          acc[n][m] = __builtin_amdgcn_mfma_f32_16x16x32_bf16(bfr[n], af[m], acc[n][m], 0, 0, 0);
    }
    __syncthreads();
  }

  // swapped layout: row r = row0+wr*64+m*16+c15 ; col c = col0+wc*64+n*16+h4*4+i
  int rb = row0 + wr*64 + c15;
  int cb = col0 + wc*64 + h4*4;
  #pragma unroll
  for (int m = 0; m < 4; m++) {
    int r = rb + m*16;
    if constexpr (EPI == 0) {
      #pragma unroll
      for (int n = 0; n < 4; n++) {
        int c0 = cb + n*16;
        f32x4 v = acc[n][m];
        f32x4 b4 = *(const f32x4*)&bias[c0];
        float scl = (c0 < CDIM) ? ATTSCALE : 1.f;
        s16x4 o;
        #pragma unroll
        for (int i = 0; i < 4; i++) o[i] = f2bfs((v[i] + b4[i]) * scl);
        *(s16x4*)&outb[(size_t)r*QKVC + c0] = o;
      }
    } else if constexpr (EPI == 1) {
      int b_ = r / NTOK, nn = r % NTOK;
      int b = b_ >> 4, wi = b_ & 15, wh = wi >> 2, ww = wi & 3;
      int ii = nn / WSZ, jj = nn % WSZ;
      int hh = (wh*WSZ + ii + SSZ) % HDIM;
      int wcc = (ww*WSZ + jj + SSZ) % WDIM;
      size_t rr = ((size_t)b*LDIM + hh*WDIM + wcc) * CDIM;
      #pragma unroll
      for (int n = 0; n < 4; n++) {
        int c0 = cb + n*16;
        f32x4 v = acc[n][m];
        f32x4 b4 = *(const f32x4*)&bias[c0];
        f32x4 a4 = *(const f32x4*)&aux[rr + c0];
        s16x4 o;
        #pragma unroll
        for (int i = 0; i < 4; i++) o[i] = f2bfs(a4[i] + v[i] + b4[i]);
        *(s16x4*)&outb[rr + c0] = o;
      }
    } else if constexpr (EPI == 2) {
      #pragma unroll
      for (int n = 0; n < 4; n++) {
        int c0 = cb + n*16;
        f32x4 v = acc[n][m];
        f32x4 b4 = *(const f32x4*)&bias[c0];
        s16x4 o;
        #pragma unroll
        for (int i = 0; i < 4; i++) {
          float val = v[i] + b4[i];
          val = 0.5f * val * (1.0f + erff(val * 0.70710678118654752f));
          o[i] = f2bfs(val);
        }
        *(s16x4*)&outb[(size_t)r*HIDDIM + c0] = o;
      }
    } else {
      #pragma unroll
      for (int n = 0; n < 4; n++) {
        int c0 = cb + n*16;
        f32x4 v = acc[n][m];
        f32x4 b4 = *(const f32x4*)&bias[c0];
        s16x4 ab = *(const s16x4*)&auxb[(size_t)r*CDIM + c0];
        f32x4 o;
        #pragma unroll
        for (int i = 0; i < 4; i++) o[i] = v[i] + b4[i] + bfs2f(ab[i]);
        *(f32x4*)&outf[(size_t)r*CDIM + c0] = o;
      }
    }
  }
}

// ---------------- MFMA fused window attention ----------------
// Wave-independent strip loop: Ps[wid] is WAVE-PRIVATE, so no block barriers
// in the main loop — only a wave-local lgkmcnt fence between P ds_writes and
// PV ds_reads (rule #18 insurance; types are short-consistent so alias
// analysis also orders them). Staging barrier before first Ks/Vt/tab2 use.
// no-max softmax (scores bounded ~|2|; masked/-1e30 pad underflow to 0).
__global__ __launch_bounds__(256) void k_attn_mfma(const bf16* __restrict__ qkv,
    const float* __restrict__ rt, bf16* __restrict__ out)
{
  __shared__ short  Ks[208*KROW];   // [m][k], rows 196..207 zero, padded stride
  __shared__ short  Vt[32*VROW];    // [d][m], cols 196..223 zero, padded stride
  __shared__ short  Ps[4][16*PROW]; // per-wave P strip [row][m], padded stride
  __shared__ float2 tab2[729];      // {bias, rscale} per rel-idx for this head
  __shared__ int    regv[208];

  int blk = blockIdx.x;
  int b_ = blk / NHEAD, head = blk % NHEAD;
  int tid = threadIdx.x, lane = tid & 63, wid = tid >> 6;
  int c15 = lane & 15, h4 = lane >> 4;

  // ---- staging ----
  const bf16* rowbase = qkv + (size_t)b_*NTOK*QKVC + head*HDHEAD;
  const bf16* kp = rowbase + CDIM;      // k block
  const bf16* vp = rowbase + 2*CDIM;    // v block
  for (int c = tid; c < 784; c += 256) {          // 196 rows x 4 chunks of 8
    int m = c >> 2, k8 = (c & 3) * 8;
    *(bf16x8*)&Ks[m*KROW + k8] = *(const bf16x8*)(kp + (size_t)m*QKVC + k8);
    bf16x8 vv = *(const bf16x8*)(vp + (size_t)m*QKVC + k8);
    #pragma unroll
    for (int j = 0; j < 8; j++) Vt[(k8+j)*VROW + m] = vv[j];
  }
  for (int e = tid; e < 12*KROW; e += 256) Ks[196*KROW + e] = 0;
  for (int e = tid; e < 32*28; e += 256) Vt[(e/28)*VROW + 196 + (e%28)] = 0;
  for (int e = tid; e < 729; e += 256)
    tab2[e] = make_float2(rt[e*2*NHEAD + head], rt[e*2*NHEAD + NHEAD + head]);
  {
    int wi = b_ & 15, wh = wi >> 2, ww = wi & 3;
    for (int e = tid; e < 208; e += 256) {
      int rv = 0;
      if (e < NTOK) {
        int i = e / WSZ, j = e % WSZ;
        int ha = wh*WSZ + i, wa = ww*WSZ + j;
        int rh = ha < (HDIM-WSZ) ? 0 : (ha < (HDIM-SSZ) ? 1 : 2);
        int rw = wa < (WDIM-WSZ) ? 0 : (wa < (WDIM-SSZ) ? 1 : 2);
        rv = rh*3 + rw;
      }
      regv[e] = rv;
    }
  }
  __syncthreads();

  // per-lane m-column constants (m = t*16 + c15)
  int   moff[13], mreg[13];
  float mpad[13];
  #pragma unroll
  for (int t = 0; t < 13; t++) {
    int m  = t*16 + c15;
    int mm = min(m, NTOK-1);
    moff[t] = (mm/WSZ)*27 + (mm%WSZ);
    mreg[t] = regv[mm];
    mpad[t] = (m >= NTOK) ? -1e30f : 0.f;
  }

  short* myP = &Ps[wid][0];
  // zero pad cols 208..223 once (never overwritten: softmax writes cols 0..207)
  #pragma unroll
  for (int i = 0; i < 4; i++) myP[(h4*4+i)*PROW + 208 + c15] = 0;

  bf16* op = out + (size_t)b_*NTOK*CDIM + head*HDHEAD;

  for (int s = wid; s < 13; s += 4) {             // wave-independent strips
    int qrow = min(s*16 + c15, NTOK-1);
    bf16x8 qf = *(const bf16x8*)(rowbase + (size_t)qrow*QKVC + h4*8);

    f32x4 sc[13];
    #pragma unroll
    for (int t = 0; t < 13; t++) {
      bf16x8 kf = *(const bf16x8*)&Ks[(t*16 + c15)*KROW + h4*8];
      sc[t] = __builtin_amdgcn_mfma_f32_16x16x32_bf16(qf, kf, (f32x4){0.f,0.f,0.f,0.f}, 0, 0, 0);
    }

    #pragma unroll
    for (int i = 0; i < 4; i++) {
      int n  = s*16 + h4*4 + i;
      int nc = min(n, NTOK-1);
      int nbase = ((nc/WSZ) + 13)*27 + (nc%WSZ) + 13;
      int nreg  = regv[nc];
      float rr[13];
      float sum = 0.f;
      #pragma unroll
      for (int t = 0; t < 13; t++) {
        float2 hr = tab2[nbase - moff[t]];
        float sv = sc[t][i] + hr.x + ((mreg[t] != nreg) ? -100.f : 0.f) + mpad[t];
        float e = __expf(sv);          // no-max softmax: |sv| tiny or -> 0
        rr[t] = hr.y;
        sc[t][i] = e; sum += e;
      }
      #pragma unroll
      for (int o = 1; o < 16; o <<= 1) sum += __shfl_xor(sum, o);
      float inv = 1.f / sum;
      int prow = h4*4 + i;
      #pragma unroll
      for (int t = 0; t < 13; t++)
        myP[prow*PROW + t*16 + c15] = f2bfs(sc[t][i] * inv * rr[t]);  // short store
    }

    // wave-local fence: drain this wave's P ds_writes before its PV ds_reads
    asm volatile("s_waitcnt lgkmcnt(0)" ::: "memory");
    __builtin_amdgcn_sched_barrier(0);

    // PV: O[16 x 32] = P[16 x 224] @ Vt^T
    f32x4 o0 = {0.f,0.f,0.f,0.f}, o1 = {0.f,0.f,0.f,0.f};
    #pragma unroll
    for (int t7 = 0; t7 < 7; t7++) {
      bf16x8 pf = *(const bf16x8*)&myP[c15*PROW + t7*32 + h4*8];
      bf16x8 v0 = *(const bf16x8*)&Vt[c15*VROW + t7*32 + h4*8];
      bf16x8 v1 = *(const bf16x8*)&Vt[(16 + c15)*VROW + t7*32 + h4*8];
      o0 = __builtin_amdgcn_mfma_f32_16x16x32_bf16(pf, v0, o0, 0, 0, 0);
      o1 = __builtin_amdgcn_mfma_f32_16x16x32_bf16(pf, v1, o1, 0, 0, 0);
    }

    #pragma unroll
    for (int i = 0; i < 4; i++) {
      int n = s*16 + h4*4 + i;
      if (n < NTOK) {
        op[(size_t)n*CDIM + c15]      = __float2bfloat16(o0[i]);
        op[(size_t)n*CDIM + 16 + c15] = __float2bfloat16(o1[i]);
      }
    }
  }
}

// ---------------- launch ----------------
extern "C" void kernel_launch(void* const* d_in, const int* in_sizes, int n_in,
                              void* d_out, int out_size, void* d_ws, size_t ws_size,
                              hipStream_t stream)
{
  const float* x      = (const float*)d_in[0];
  const float* n1w    = (const float*)d_in[1];
  const float* n1b    = (const float*)d_in[2];
  const float* qkv_w  = (const float*)d_in[3];
  const float* qkv_b  = (const float*)d_in[4];
  const float* proj_w = (const float*)d_in[5];
  const float* proj_b = (const float*)d_in[6];
  const float* rt     = (const float*)d_in[7];
  const float* n2w    = (const float*)d_in[8];
  const float* n2b    = (const float*)d_in[9];
  const float* fc1_w  = (const float*)d_in[10];
  const float* fc1_b  = (const float*)d_in[11];
  const float* fc2_w  = (const float*)d_in[12];
  const float* fc2_b  = (const float*)d_in[13];

  char* ws = (char*)d_ws;
  const size_t SZ_BF = (size_t)MROWS * CDIM * 2;   // 77,070,336 B
  // arena (total exactly 8*SZ_BF, proven footprint):
  //  R0 [0,1SZ):    xw -> attnout -> (after proj) wf1,wf2
  //  R1 [1SZ,4SZ):  qkv (contiguous [r][1152]) -> x2(bf16,[1SZ,2SZ)) + hln([2SZ,3SZ))
  //  R2 [4SZ,8SZ):  wq,wp (head) -> hid (overwrites dead wq/wp at fc1)
  bf16*  xw      = (bf16*)ws;
  bf16*  attnout = (bf16*)ws;
  bf16*  qkv     = (bf16*)(ws + SZ_BF);
  bf16*  x2b     = (bf16*)(ws + SZ_BF);
  bf16*  hln     = (bf16*)(ws + 2*SZ_BF);
  bf16*  hid     = (bf16*)(ws + 4*SZ_BF);
  const int NQKVW = 3*CDIM*CDIM;      // 442368
  const int NPROJW = CDIM*CDIM;       // 147456
  const int NFCW  = HIDDIM*CDIM;      // 589824
  bf16* wq  = (bf16*)(ws + 4*SZ_BF);  // lives in R2 until fc1 clobbers it
  bf16* wp  = wq + NQKVW;
  bf16* wf1 = (bf16*)ws;              // converted into R0 after proj GEMM
  bf16* wf2 = wf1 + NFCW;

  k_cvt<<<(NQKVW+255)/256, 256, 0, stream>>>(qkv_w, wq, NQKVW);
  k_cvt<<<(NPROJW+255)/256, 256, 0, stream>>>(proj_w, wp, NPROJW);

  k_ln<true, float><<<MROWS, 128, 0, stream>>>(x, n1w, n1b, xw);
  k_mgemm<CDIM, 0><<<(MROWS/256)*9, 512, 0, stream>>>(
      xw, wq, qkv_b, nullptr, nullptr, nullptr, qkv, 9);
  k_attn_mfma<<<BWIN*NHEAD, 256, 0, stream>>>(qkv, rt, attnout);
  k_mgemm<CDIM, 1><<<(MROWS/256)*3, 512, 0, stream>>>(
      attnout, wp, proj_b, x, nullptr, nullptr, x2b, 3);

  k_cvt<<<(NFCW+255)/256, 256, 0, stream>>>(fc1_w, wf1, NFCW);
  k_cvt<<<(NFCW+255)/256, 256, 0, stream>>>(fc2_w, wf2, NFCW);

  k_ln<false, bf16><<<MROWS, 128, 0, stream>>>(x2b, n2w, n2b, hln);
  k_mgemm<CDIM, 2><<<(MROWS/256)*12, 512, 0, stream>>>(
      hln, wf1, fc1_b, nullptr, nullptr, nullptr, hid, 12);
  k_mgemm<HIDDIM, 3><<<(MROWS/256)*3, 512, 0, stream>>>(
      hid, wf2, fc2_b, nullptr, x2b, (float*)d_out, nullptr, 3);
}

// Round 12
// 1032.537 us; speedup vs baseline: 1.0807x; 1.0025x over previous
//
#include <hip/hip_runtime.h>
#include <hip/hip_bf16.h>
#include <math.h>

// ---------------- problem constants ----------------
#define BDIM 32
#define HDIM 56
#define WDIM 56
#define CDIM 384
#define NHEAD 12
#define WSZ 14
#define SSZ 7
#define LDIM (HDIM*WDIM)        // 3136
#define NTOK (WSZ*WSZ)          // 196
#define HDHEAD (CDIM/NHEAD)     // 32
#define HIDDIM (4*CDIM)         // 1536
#define NWIN 16
#define BWIN (BDIM*NWIN)        // 512
#define MROWS (BDIM*LDIM)       // 100352 == BWIN*NTOK
#define EPSLN 1e-5f
#define ATTSCALE 0.17677669529663687f   // 32^-0.5
#define QKVC (3*CDIM)           // 1152, contiguous qkv row stride
#define TBLM 224                // table m' extent (196 real + pad -> -inf)

// padded LDS strides (shorts) for attention
#define KROW 40
#define VROW 232
#define PROW 232

typedef __hip_bfloat16 bf16;
typedef __attribute__((ext_vector_type(8))) short bf16x8;   // 8 bf16 = 4 VGPRs
typedef __attribute__((ext_vector_type(4))) short s16x4;    // 4 bf16 = 1 b64 store
typedef __attribute__((ext_vector_type(2))) short s16x2;
typedef __attribute__((ext_vector_type(4))) float f32x4;

// async global->LDS, 16B per lane, wave-uniform LDS base
#define ASYNC16(gp, lp) __builtin_amdgcn_global_load_lds( \
    (__attribute__((address_space(1))) void*)(gp),        \
    (__attribute__((address_space(3))) void*)(lp), 16, 0, 0)

// float -> bf16 bit pattern as short (type-consistent with short LDS arrays)
static __device__ __forceinline__ short f2bfs(float x) {
  union { bf16 h; short s; } u; u.h = __float2bfloat16(x); return u.s;
}
static __device__ __forceinline__ float bfs2f(short s) {
  unsigned int u = ((unsigned int)(unsigned short)s) << 16;
  float f; __builtin_memcpy(&f, &u, 4); return f;
}

// ---------------- fp32 -> bf16 weight convert ----------------
__global__ __launch_bounds__(256) void k_cvt(const float* __restrict__ in,
                                             bf16* __restrict__ out, int n)
{
  int i = blockIdx.x * 256 + threadIdx.x;
  if (i < n) out[i] = __float2bfloat16(in[i]);
}

// ---------------- attention bias/rscale table build ----------------
// tbl[wi][head][n][m'] (u32) = lo: bf16(bias[head][n][m'] + mask(wi,n,m'))
//                              hi: bf16(rscale[head][n][m'])
// m' in [196,224) -> lo = bf16 -inf (exp -> 0), hi = 0.
__global__ __launch_bounds__(256) void k_btab(const float* __restrict__ rt,
                                              unsigned int* __restrict__ tbl)
{
  int idx = blockIdx.x*256 + threadIdx.x;        // 16*12*196*224 exact
  int mp   = idx % TBLM;
  int rest = idx / TBLM;
  int n    = rest % NTOK;  rest /= NTOK;
  int head = rest % NHEAD;
  int wi   = rest / NHEAD;

  unsigned int outv;
  if (mp >= NTOK) {
    outv = 0x0000FF80u;                          // lo = bf16 -inf, hi = 0
  } else {
    int ni = n / WSZ,  nj = n % WSZ;
    int mi = mp / WSZ, mj = mp % WSZ;
    int ridx = (ni - mi + 13)*27 + (nj - mj + 13);
    float bias = rt[ridx*2*NHEAD + head];
    float rsc  = rt[ridx*2*NHEAD + NHEAD + head];
    int wh = wi >> 2, ww = wi & 3;
    int ha = wh*WSZ + ni, wa = ww*WSZ + nj;
    int rn = (ha < (HDIM-WSZ) ? 0 : (ha < (HDIM-SSZ) ? 1 : 2))*3
           + (wa < (WDIM-WSZ) ? 0 : (wa < (WDIM-SSZ) ? 1 : 2));
    int hb = wh*WSZ + mi, wb = ww*WSZ + mj;
    int rm = (hb < (HDIM-WSZ) ? 0 : (hb < (HDIM-SSZ) ? 1 : 2))*3
           + (wb < (WDIM-WSZ) ? 0 : (wb < (WDIM-SSZ) ? 1 : 2));
    if (rn != rm) bias -= 100.f;
    unsigned int lo = (unsigned short)f2bfs(bias);
    unsigned int hi = (unsigned short)f2bfs(rsc);
    outv = lo | (hi << 16);
  }
  tbl[idx] = outv;
}

// ---------------- LN: wave-per-row, vectorized, no LDS/barrier ----------------
// block 256 = 4 waves = 4 rows; lane covers 6 elems: [lane*4, +4) and [256+lane*2, +2)
template<bool WIN, typename TIN>
__global__ __launch_bounds__(256) void k_ln(const TIN* __restrict__ xin,
    const float* __restrict__ gw, const float* __restrict__ gb,
    bf16* __restrict__ out)
{
  int lane = threadIdx.x & 63, wid = threadIdx.x >> 6;
  int r = blockIdx.x*4 + wid;
  const TIN* xp = xin + (size_t)r * CDIM;
  float v[6];
  if constexpr (sizeof(TIN) == 4) {
    float4 a = *(const float4*)((const float*)xp + lane*4);
    float2 b = *(const float2*)((const float*)xp + 256 + lane*2);
    v[0]=a.x; v[1]=a.y; v[2]=a.z; v[3]=a.w; v[4]=b.x; v[5]=b.y;
  } else {
    s16x4 a = *(const s16x4*)((const short*)xp + lane*4);
    s16x2 b = *(const s16x2*)((const short*)xp + 256 + lane*2);
    v[0]=bfs2f(a[0]); v[1]=bfs2f(a[1]); v[2]=bfs2f(a[2]); v[3]=bfs2f(a[3]);
    v[4]=bfs2f(b[0]); v[5]=bfs2f(b[1]);
  }
  float s = 0.f, ss = 0.f;
  #pragma unroll
  for (int j = 0; j < 6; j++) { s += v[j]; ss += v[j]*v[j]; }
  #pragma unroll
  for (int o = 1; o < 64; o <<= 1) { s += __shfl_xor(s, o); ss += __shfl_xor(ss, o); }
  float mean = s * (1.0f/CDIM);
  float var  = ss * (1.0f/CDIM) - mean*mean;
  float rstd = rsqrtf(var + EPSLN);

  size_t orow;
  if (WIN) {
    int b = r / LDIM, l = r % LDIM;
    int h = l / WDIM, w = l % WDIM;
    int h2 = (h + HDIM - SSZ) % HDIM, w2 = (w + WDIM - SSZ) % WDIM;
    int wh = h2 / WSZ, ii = h2 % WSZ, ww = w2 / WSZ, jj = w2 % WSZ;
    int b_ = b*NWIN + wh*4 + ww;
    int n  = ii*WSZ + jj;
    orow = ((size_t)b_*NTOK + n) * CDIM;
  } else {
    orow = (size_t)r * CDIM;
  }
  float4 w4 = *(const float4*)(gw + lane*4);
  float2 w2 = *(const float2*)(gw + 256 + lane*2);
  float4 g4 = *(const float4*)(gb + lane*4);
  float2 g2 = *(const float2*)(gb + 256 + lane*2);
  s16x4 o4;
  o4[0] = f2bfs((v[0]-mean)*rstd*w4.x + g4.x);
  o4[1] = f2bfs((v[1]-mean)*rstd*w4.y + g4.y);
  o4[2] = f2bfs((v[2]-mean)*rstd*w4.z + g4.z);
  o4[3] = f2bfs((v[3]-mean)*rstd*w4.w + g4.w);
  *(s16x4*)((short*)out + orow + lane*4) = o4;
  s16x2 o2;
  o2[0] = f2bfs((v[4]-mean)*rstd*w2.x + g2.x);
  o2[1] = f2bfs((v[5]-mean)*rstd*w2.y + g2.y);
  *(s16x2*)((short*)out + orow + 256 + lane*2) = o2;
}

// ---------------- MFMA GEMM: C = A(bf16,MxK) @ Wb(bf16,NCxK)^T ----------------
// 256x128 tile, 512 threads (8 waves = 4M x 2N), BK=64, single 48KB LDS buffer.
// Operand-SWAPPED MFMA + vector epilogue; both-sides XOR bank-swizzle;
// XCD-bijective 1-D grid swizzle (nwg % 8 == 0).
template<int KD, int EPI>
__global__ __launch_bounds__(512, 4) void k_mgemm(
    const bf16* __restrict__ A, const bf16* __restrict__ Wb,
    const float* __restrict__ bias, const float* __restrict__ aux,
    const bf16* __restrict__ auxb,
    float* __restrict__ outf, bf16* __restrict__ outb, int gx)
{
  __shared__ short As[256*64];   // 32 KB
  __shared__ short Bs[128*64];   // 16 KB
  int tid  = threadIdx.x;
  int lane = tid & 63, wid = tid >> 6;
  int c15 = lane & 15, h4 = lane >> 4;
  int wr = wid >> 1, wc = wid & 1;          // 4 M-quarters x 2 N-halves

  int nwg = gridDim.x, bid = blockIdx.x;
  int swz = (bid & 7) * (nwg >> 3) + (bid >> 3);
  int ty = swz / gx, tx = swz - ty * gx;
  int row0 = ty * 256, col0 = tx * 128;

  f32x4 acc[4][4] = {};          // [n][m]

  int srow = lane >> 3;                       // 0..7 within chunk
  int skk  = ((lane & 7) ^ srow) * 8;         // pre-swizzled global k-offset

  const int NT = KD / 64;

  for (int t = 0; t < NT; t++) {
    int k0 = t * 64;
    #pragma unroll
    for (int s = 0; s < 4; s++) {             // A: 32 chunks, 4 per wave
      int c = wid*4 + s;
      ASYNC16(A + (size_t)(row0 + c*8 + srow)*KD + k0 + skk, &As[c*512]);
    }
    #pragma unroll
    for (int s = 0; s < 2; s++) {             // B: 16 chunks, 2 per wave
      int c = wid*2 + s;
      ASYNC16(Wb + (size_t)(col0 + c*8 + srow)*KD + k0 + skk, &Bs[c*512]);
    }
    __syncthreads();

    #pragma unroll
    for (int half = 0; half < 2; half++) {
      bf16x8 af[4], bfr[4];
      int blk8 = ((half << 2) + h4) ^ (c15 & 7);   // swizzled read block
      #pragma unroll
      for (int m = 0; m < 4; m++) {
        int rr = wr*64 + m*16 + c15;
        af[m] = *reinterpret_cast<const bf16x8*>(&As[rr*64 + blk8*8]);
      }
      #pragma unroll
      for (int n = 0; n < 4; n++) {
        int rr = wc*64 + n*16 + c15;
        bfr[n] = *reinterpret_cast<const bf16x8*>(&Bs[rr*64 + blk8*8]);
      }
      #pragma unroll
      for (int n = 0; n < 4; n++)
        #pragma unroll
        for (int m = 0; m < 4; m++)
          acc[n][m] = __builtin_amdgcn_mfma_f32_16x16x32_bf16(bfr[n], af[m], acc[n][m], 0, 0, 0);
    }
    __syncthreads();
  }

  int rb = row0 + wr*64 + c15;
  int cb = col0 + wc*64 + h4*4;
  #pragma unroll
  for (int m = 0; m < 4; m++) {
    int r = rb + m*16;
    if constexpr (EPI == 0) {
      #pragma unroll
      for (int n = 0; n < 4; n++) {
        int c0 = cb + n*16;
        f32x4 v = acc[n][m];
        f32x4 b4 = *(const f32x4*)&bias[c0];
        float scl = (c0 < CDIM) ? ATTSCALE : 1.f;
        s16x4 o;
        #pragma unroll
        for (int i = 0; i < 4; i++) o[i] = f2bfs((v[i] + b4[i]) * scl);
        *(s16x4*)&outb[(size_t)r*QKVC + c0] = o;
      }
    } else if constexpr (EPI == 1) {
      int b_ = r / NTOK, nn = r % NTOK;
      int b = b_ >> 4, wi = b_ & 15, wh = wi >> 2, ww = wi & 3;
      int ii = nn / WSZ, jj = nn % WSZ;
      int hh = (wh*WSZ + ii + SSZ) % HDIM;
      int wcc = (ww*WSZ + jj + SSZ) % WDIM;
      size_t rr = ((size_t)b*LDIM + hh*WDIM + wcc) * CDIM;
      #pragma unroll
      for (int n = 0; n < 4; n++) {
        int c0 = cb + n*16;
        f32x4 v = acc[n][m];
        f32x4 b4 = *(const f32x4*)&bias[c0];
        f32x4 a4 = *(const f32x4*)&aux[rr + c0];
        s16x4 o;
        #pragma unroll
        for (int i = 0; i < 4; i++) o[i] = f2bfs(a4[i] + v[i] + b4[i]);
        *(s16x4*)&outb[rr + c0] = o;
      }
    } else if constexpr (EPI == 2) {
      #pragma unroll
      for (int n = 0; n < 4; n++) {
        int c0 = cb + n*16;
        f32x4 v = acc[n][m];
        f32x4 b4 = *(const f32x4*)&bias[c0];
        s16x4 o;
        #pragma unroll
        for (int i = 0; i < 4; i++) {
          float val = v[i] + b4[i];
          val = 0.5f * val * (1.0f + erff(val * 0.70710678118654752f));
          o[i] = f2bfs(val);
        }
        *(s16x4*)&outb[(size_t)r*HIDDIM + c0] = o;
      }
    } else {
      #pragma unroll
      for (int n = 0; n < 4; n++) {
        int c0 = cb + n*16;
        f32x4 v = acc[n][m];
        f32x4 b4 = *(const f32x4*)&bias[c0];
        s16x4 ab = *(const s16x4*)&auxb[(size_t)r*CDIM + c0];
        f32x4 o;
        #pragma unroll
        for (int i = 0; i < 4; i++) o[i] = v[i] + b4[i] + bfs2f(ab[i]);
        *(f32x4*)&outf[(size_t)r*CDIM + c0] = o;
      }
    }
  }
}

// ---------------- MFMA fused window attention ----------------
// Wave-independent strip loop (Ps wave-private). Bias+mask+rscale from the
// precomputed u32 table (coalesced L2-resident loads) — no tab2/regv gathers.
// Chunked XCD swizzle: each XCD gets contiguous windows (L2 line reuse).
__global__ __launch_bounds__(256) void k_attn_mfma(const bf16* __restrict__ qkv,
    const unsigned int* __restrict__ tbl, bf16* __restrict__ out)
{
  __shared__ short  Ks[208*KROW];   // [m][k], rows 196..207 zero, padded stride
  __shared__ short  Vt[32*VROW];    // [d][m], cols 196..223 zero, padded stride
  __shared__ short  Ps[4][16*PROW]; // per-wave P strip [row][m], padded stride

  int bid = blockIdx.x;
  int blk = (bid & 7) * 768 + (bid >> 3);   // chunked XCD swizzle (6144/8=768)
  int b_ = blk / NHEAD, head = blk % NHEAD;
  int tid = threadIdx.x, lane = tid & 63, wid = tid >> 6;
  int c15 = lane & 15, h4 = lane >> 4;

  // ---- staging ----
  const bf16* rowbase = qkv + (size_t)b_*NTOK*QKVC + head*HDHEAD;
  const bf16* kp = rowbase + CDIM;      // k block
  const bf16* vp = rowbase + 2*CDIM;    // v block
  for (int c = tid; c < 784; c += 256) {          // 196 rows x 4 chunks of 8
    int m = c >> 2, k8 = (c & 3) * 8;
    *(bf16x8*)&Ks[m*KROW + k8] = *(const bf16x8*)(kp + (size_t)m*QKVC + k8);
    bf16x8 vv = *(const bf16x8*)(vp + (size_t)m*QKVC + k8);
    #pragma unroll
    for (int j = 0; j < 8; j++) Vt[(k8+j)*VROW + m] = vv[j];
  }
  for (int e = tid; e < 12*KROW; e += 256) Ks[196*KROW + e] = 0;
  for (int e = tid; e < 32*28; e += 256) Vt[(e/28)*VROW + 196 + (e%28)] = 0;
  __syncthreads();

  const unsigned int* tblbh = tbl + (size_t)((b_ & 15)*NHEAD + head)*NTOK*TBLM;

  short* myP = &Ps[wid][0];
  // zero pad cols 208..223 once (never overwritten: softmax writes cols 0..207)
  #pragma unroll
  for (int i = 0; i < 4; i++) myP[(h4*4+i)*PROW + 208 + c15] = 0;

  bf16* op = out + (size_t)b_*NTOK*CDIM + head*HDHEAD;

  for (int s = wid; s < 13; s += 4) {             // wave-independent strips
    int qrow = min(s*16 + c15, NTOK-1);
    bf16x8 qf = *(const bf16x8*)(rowbase + (size_t)qrow*QKVC + h4*8);

    f32x4 sc[13];
    #pragma unroll
    for (int t = 0; t < 13; t++) {
      bf16x8 kf = *(const bf16x8*)&Ks[(t*16 + c15)*KROW + h4*8];
      sc[t] = __builtin_amdgcn_mfma_f32_16x16x32_bf16(qf, kf, (f32x4){0.f,0.f,0.f,0.f}, 0, 0, 0);
    }

    #pragma unroll
    for (int i = 0; i < 4; i++) {
      int n  = s*16 + h4*4 + i;
      int ncl = min(n, NTOK-1);
      const unsigned int* trow = tblbh + (size_t)ncl*TBLM;
      float sum = 0.f;
      #pragma unroll
      for (int t = 0; t < 13; t++) {
        unsigned int tv = trow[t*16 + c15];
        float bv = bfs2f((short)(tv & 0xFFFFu));
        float e = __expf(sc[t][i] + bv);          // no-max softmax; -inf -> 0
        sum += e;
        sc[t][i] = e * bfs2f((short)(tv >> 16));  // fold rscale pre-normalize
      }
      #pragma unroll
      for (int o = 1; o < 16; o <<= 1) sum += __shfl_xor(sum, o);
      float inv = 1.f / sum;
      int prow = h4*4 + i;
      #pragma unroll
      for (int t = 0; t < 13; t++)
        myP[prow*PROW + t*16 + c15] = f2bfs(sc[t][i] * inv);   // short store
    }

    // wave-local fence: drain this wave's P ds_writes before its PV ds_reads
    asm volatile("s_waitcnt lgkmcnt(0)" ::: "memory");
    __builtin_amdgcn_sched_barrier(0);

    // PV: O[16 x 32] = P[16 x 224] @ Vt^T
    f32x4 o0 = {0.f,0.f,0.f,0.f}, o1 = {0.f,0.f,0.f,0.f};
    #pragma unroll
    for (int t7 = 0; t7 < 7; t7++) {
      bf16x8 pf = *(const bf16x8*)&myP[c15*PROW + t7*32 + h4*8];
      bf16x8 v0 = *(const bf16x8*)&Vt[c15*VROW + t7*32 + h4*8];
      bf16x8 v1 = *(const bf16x8*)&Vt[(16 + c15)*VROW + t7*32 + h4*8];
      o0 = __builtin_amdgcn_mfma_f32_16x16x32_bf16(pf, v0, o0, 0, 0, 0);
      o1 = __builtin_amdgcn_mfma_f32_16x16x32_bf16(pf, v1, o1, 0, 0, 0);
    }

    #pragma unroll
    for (int i = 0; i < 4; i++) {
      int n = s*16 + h4*4 + i;
      if (n < NTOK) {
        op[(size_t)n*CDIM + c15]      = __float2bfloat16(o0[i]);
        op[(size_t)n*CDIM + 16 + c15] = __float2bfloat16(o1[i]);
      }
    }
  }
}

// ---------------- launch ----------------
extern "C" void kernel_launch(void* const* d_in, const int* in_sizes, int n_in,
                              void* d_out, int out_size, void* d_ws, size_t ws_size,
                              hipStream_t stream)
{
  const float* x      = (const float*)d_in[0];
  const float* n1w    = (const float*)d_in[1];
  const float* n1b    = (const float*)d_in[2];
  const float* qkv_w  = (const float*)d_in[3];
  const float* qkv_b  = (const float*)d_in[4];
  const float* proj_w = (const float*)d_in[5];
  const float* proj_b = (const float*)d_in[6];
  const float* rt     = (const float*)d_in[7];
  const float* n2w    = (const float*)d_in[8];
  const float* n2b    = (const float*)d_in[9];
  const float* fc1_w  = (const float*)d_in[10];
  const float* fc1_b  = (const float*)d_in[11];
  const float* fc2_w  = (const float*)d_in[12];
  const float* fc2_b  = (const float*)d_in[13];

  char* ws = (char*)d_ws;
  const size_t SZ_BF = (size_t)MROWS * CDIM * 2;   // 77,070,336 B
  // arena (total exactly 8*SZ_BF, proven footprint):
  //  R0 [0,1SZ):    xw -> attnout -> (after proj) wf1,wf2
  //  R1 [1SZ,4SZ):  qkv (contiguous [r][1152]) -> x2(bf16,[1SZ,2SZ)) + hln([2SZ,3SZ))
  //  R2 [4SZ,8SZ):  wq,wp (at 4SZ) + bias table (at 5SZ, dead at fc1) -> hid
  bf16*  xw      = (bf16*)ws;
  bf16*  attnout = (bf16*)ws;
  bf16*  qkv     = (bf16*)(ws + SZ_BF);
  bf16*  x2b     = (bf16*)(ws + SZ_BF);
  bf16*  hln     = (bf16*)(ws + 2*SZ_BF);
  bf16*  hid     = (bf16*)(ws + 4*SZ_BF);
  const int NQKVW = 3*CDIM*CDIM;      // 442368
  const int NPROJW = CDIM*CDIM;       // 147456
  const int NFCW  = HIDDIM*CDIM;      // 589824
  bf16* wq  = (bf16*)(ws + 4*SZ_BF);  // lives in R2 until fc1 clobbers it
  bf16* wp  = wq + NQKVW;
  bf16* wf1 = (bf16*)ws;              // converted into R0 after proj GEMM
  bf16* wf2 = wf1 + NFCW;
  unsigned int* tbl = (unsigned int*)(ws + 5*SZ_BF);  // 33.7 MB, dead at fc1

  k_cvt<<<(NQKVW+255)/256, 256, 0, stream>>>(qkv_w, wq, NQKVW);
  k_cvt<<<(NPROJW+255)/256, 256, 0, stream>>>(proj_w, wp, NPROJW);
  k_btab<<<(NWIN*NHEAD*NTOK*TBLM)/256, 256, 0, stream>>>(rt, tbl);

  k_ln<true, float><<<MROWS/4, 256, 0, stream>>>(x, n1w, n1b, xw);
  k_mgemm<CDIM, 0><<<(MROWS/256)*9, 512, 0, stream>>>(
      xw, wq, qkv_b, nullptr, nullptr, nullptr, qkv, 9);
  k_attn_mfma<<<BWIN*NHEAD, 256, 0, stream>>>(qkv, tbl, attnout);
  k_mgemm<CDIM, 1><<<(MROWS/256)*3, 512, 0, stream>>>(
      attnout, wp, proj_b, x, nullptr, nullptr, x2b, 3);

  k_cvt<<<(NFCW+255)/256, 256, 0, stream>>>(fc1_w, wf1, NFCW);
  k_cvt<<<(NFCW+255)/256, 256, 0, stream>>>(fc2_w, wf2, NFCW);

  k_ln<false, bf16><<<MROWS/4, 256, 0, stream>>>(x2b, n2w, n2b, hln);
  k_mgemm<CDIM, 2><<<(MROWS/256)*12, 512, 0, stream>>>(
      hln, wf1, fc1_b, nullptr, nullptr, nullptr, hid, 12);
  k_mgemm<HIDDIM, 3><<<(MROWS/256)*3, 512, 0, stream>>>(
      hid, wf2, fc2_b, nullptr, x2b, (float*)d_out, nullptr, 3);
}

// Round 13
// 1012.223 us; speedup vs baseline: 1.1023x; 1.0201x over previous
//
#include <hip/hip_runtime.h>
#include <hip/hip_bf16.h>
#include <math.h>

// ---------------- problem constants ----------------
#define BDIM 32
#define HDIM 56
#define WDIM 56
#define CDIM 384
#define NHEAD 12
#define WSZ 14
#define SSZ 7
#define LDIM (HDIM*WDIM)        // 3136
#define NTOK (WSZ*WSZ)          // 196
#define HDHEAD (CDIM/NHEAD)     // 32
#define HIDDIM (4*CDIM)         // 1536
#define NWIN 16
#define BWIN (BDIM*NWIN)        // 512
#define MROWS (BDIM*LDIM)       // 100352 == BWIN*NTOK
#define EPSLN 1e-5f
#define ATTSCALE 0.17677669529663687f   // 32^-0.5
#define QKVC (3*CDIM)           // 1152, contiguous qkv row stride

// padded LDS strides (shorts) for attention
#define KROW 40
#define VROW 232
#define PROW 232

typedef __hip_bfloat16 bf16;
typedef __attribute__((ext_vector_type(8))) short bf16x8;   // 8 bf16 = 4 VGPRs
typedef __attribute__((ext_vector_type(4))) short s16x4;    // 4 bf16 = 1 b64 store
typedef __attribute__((ext_vector_type(2))) short s16x2;
typedef __attribute__((ext_vector_type(4))) float f32x4;

// async global->LDS, 16B per lane, wave-uniform LDS base
#define ASYNC16(gp, lp) __builtin_amdgcn_global_load_lds( \
    (__attribute__((address_space(1))) void*)(gp),        \
    (__attribute__((address_space(3))) void*)(lp), 16, 0, 0)

// float -> bf16 bit pattern as short (type-consistent with short LDS arrays)
static __device__ __forceinline__ short f2bfs(float x) {
  union { bf16 h; short s; } u; u.h = __float2bfloat16(x); return u.s;
}
static __device__ __forceinline__ float bfs2f(short s) {
  unsigned int u = ((unsigned int)(unsigned short)s) << 16;
  float f; __builtin_memcpy(&f, &u, 4); return f;
}

// ---------------- fp32 -> bf16 weight convert ----------------
__global__ __launch_bounds__(256) void k_cvt(const float* __restrict__ in,
                                             bf16* __restrict__ out, int n)
{
  int i = blockIdx.x * 256 + threadIdx.x;
  if (i < n) out[i] = __float2bfloat16(in[i]);
}

// ---------------- LN: wave-per-row, vectorized, no LDS/barrier ----------------
template<bool WIN, typename TIN>
__global__ __launch_bounds__(256) void k_ln(const TIN* __restrict__ xin,
    const float* __restrict__ gw, const float* __restrict__ gb,
    bf16* __restrict__ out)
{
  int lane = threadIdx.x & 63, wid = threadIdx.x >> 6;
  int r = blockIdx.x*4 + wid;
  const TIN* xp = xin + (size_t)r * CDIM;
  float v[6];
  if constexpr (sizeof(TIN) == 4) {
    float4 a = *(const float4*)((const float*)xp + lane*4);
    float2 b = *(const float2*)((const float*)xp + 256 + lane*2);
    v[0]=a.x; v[1]=a.y; v[2]=a.z; v[3]=a.w; v[4]=b.x; v[5]=b.y;
  } else {
    s16x4 a = *(const s16x4*)((const short*)xp + lane*4);
    s16x2 b = *(const s16x2*)((const short*)xp + 256 + lane*2);
    v[0]=bfs2f(a[0]); v[1]=bfs2f(a[1]); v[2]=bfs2f(a[2]); v[3]=bfs2f(a[3]);
    v[4]=bfs2f(b[0]); v[5]=bfs2f(b[1]);
  }
  float s = 0.f, ss = 0.f;
  #pragma unroll
  for (int j = 0; j < 6; j++) { s += v[j]; ss += v[j]*v[j]; }
  #pragma unroll
  for (int o = 1; o < 64; o <<= 1) { s += __shfl_xor(s, o); ss += __shfl_xor(ss, o); }
  float mean = s * (1.0f/CDIM);
  float var  = ss * (1.0f/CDIM) - mean*mean;
  float rstd = rsqrtf(var + EPSLN);

  size_t orow;
  if (WIN) {
    int b = r / LDIM, l = r % LDIM;
    int h = l / WDIM, w = l % WDIM;
    int h2 = (h + HDIM - SSZ) % HDIM, w2 = (w + WDIM - SSZ) % WDIM;
    int wh = h2 / WSZ, ii = h2 % WSZ, ww = w2 / WSZ, jj = w2 % WSZ;
    int b_ = b*NWIN + wh*4 + ww;
    int n  = ii*WSZ + jj;
    orow = ((size_t)b_*NTOK + n) * CDIM;
  } else {
    orow = (size_t)r * CDIM;
  }
  float4 w4 = *(const float4*)(gw + lane*4);
  float2 w2 = *(const float2*)(gw + 256 + lane*2);
  float4 g4 = *(const float4*)(gb + lane*4);
  float2 g2 = *(const float2*)(gb + 256 + lane*2);
  s16x4 o4;
  o4[0] = f2bfs((v[0]-mean)*rstd*w4.x + g4.x);
  o4[1] = f2bfs((v[1]-mean)*rstd*w4.y + g4.y);
  o4[2] = f2bfs((v[2]-mean)*rstd*w4.z + g4.z);
  o4[3] = f2bfs((v[3]-mean)*rstd*w4.w + g4.w);
  *(s16x4*)((short*)out + orow + lane*4) = o4;
  s16x2 o2;
  o2[0] = f2bfs((v[4]-mean)*rstd*w2.x + g2.x);
  o2[1] = f2bfs((v[5]-mean)*rstd*w2.y + g2.y);
  *(s16x2*)((short*)out + orow + 256 + lane*2) = o2;
}

// ---------------- MFMA GEMM: C = A(bf16,MxK) @ Wb(bf16,NCxK)^T ----------------
// 256x128 tile, 512 threads (8 waves = 4M x 2N), BK=32, DOUBLE-buffered 48 KB
// LDS, counted-vmcnt pipeline (T4): raw s_barrier + s_waitcnt vmcnt(3) so the
// 3 prefetch loads stay in flight across the barrier (each wave waits only for
// its OWN older tile's loads; barrier then guarantees tile complete block-wide).
// Operand-SWAPPED MFMA + vector epilogue; both-sides XOR bank-swizzle with
// f(r) = (r&3)^((r>>2)&3); XCD-bijective 1-D grid swizzle (nwg % 8 == 0).
template<int KD, int EPI>
__global__ __launch_bounds__(512, 4) void k_mgemm(
    const bf16* __restrict__ A, const bf16* __restrict__ Wb,
    const float* __restrict__ bias, const float* __restrict__ aux,
    const bf16* __restrict__ auxb,
    float* __restrict__ outf, bf16* __restrict__ outb, int gx)
{
  __shared__ short As[2][256*32];   // 16 KB each
  __shared__ short Bs[2][128*32];   // 8 KB each  (total 48 KB)
  int tid  = threadIdx.x;
  int lane = tid & 63, wid = tid >> 6;
  int c15 = lane & 15, h4 = lane >> 4;
  int wr = wid >> 1, wc = wid & 1;          // 4 M-quarters x 2 N-halves

  int nwg = gridDim.x, bid = blockIdx.x;
  int swz = (bid & 7) * (nwg >> 3) + (bid >> 3);
  int ty = swz / gx, tx = swz - ty * gx;
  int row0 = ty * 256, col0 = tx * 128;

  f32x4 acc[4][4] = {};          // [n][m]

  // staging: chunk c = r*4 + b (8 shorts each). Thread t covers A chunks t and
  // t+512 (rows r0, r0+128) and B chunk t. Source k-block pre-swizzled by
  // f(r) = (r&3)^((r>>2)&3)  (identical for r0 and r0+128).
  int r0  = tid >> 2, b0 = tid & 3;
  int sk0 = (b0 ^ (r0 & 3) ^ ((r0 >> 2) & 3)) * 8;

  const int NT = KD / 32;

#define STAGE_T(k0, bf) do { \
    ASYNC16(A  + (size_t)(row0 + r0)*KD       + (k0) + sk0, &As[bf][tid*8]); \
    ASYNC16(A  + (size_t)(row0 + r0 + 128)*KD + (k0) + sk0, &As[bf][(tid+512)*8]); \
    ASYNC16(Wb + (size_t)(col0 + r0)*KD       + (k0) + sk0, &Bs[bf][tid*8]); \
  } while (0)

  STAGE_T(0, 0);                      // prologue

  int rblk = (h4 ^ (c15 & 3) ^ ((c15 >> 2) & 3)) * 8;   // swizzled read offset

  for (int t = 0; t < NT; t++) {
    int cur = t & 1;
    if (t + 1 < NT) {
      STAGE_T((t+1)*32, cur^1);
      asm volatile("s_waitcnt vmcnt(3)" ::: "memory");   // tile-t loads done
    } else {
      asm volatile("s_waitcnt vmcnt(0)" ::: "memory");
    }
    __builtin_amdgcn_s_barrier();
    __builtin_amdgcn_sched_barrier(0);

    bf16x8 af[4], bfr[4];
    #pragma unroll
    for (int m = 0; m < 4; m++)
      af[m] = *reinterpret_cast<const bf16x8*>(&As[cur][(wr*64 + m*16 + c15)*32 + rblk]);
    #pragma unroll
    for (int n = 0; n < 4; n++)
      bfr[n] = *reinterpret_cast<const bf16x8*>(&Bs[cur][(wc*64 + n*16 + c15)*32 + rblk]);
    #pragma unroll
    for (int n = 0; n < 4; n++)
      #pragma unroll
      for (int m = 0; m < 4; m++)
        acc[n][m] = __builtin_amdgcn_mfma_f32_16x16x32_bf16(bfr[n], af[m], acc[n][m], 0, 0, 0);

    __builtin_amdgcn_sched_barrier(0);
    __builtin_amdgcn_s_barrier();     // readers done before buf reuse at t+2
  }
#undef STAGE_T

  int rb = row0 + wr*64 + c15;
  int cb = col0 + wc*64 + h4*4;
  #pragma unroll
  for (int m = 0; m < 4; m++) {
    int r = rb + m*16;
    if constexpr (EPI == 0) {
      #pragma unroll
      for (int n = 0; n < 4; n++) {
        int c0 = cb + n*16;
        f32x4 v = acc[n][m];
        f32x4 b4 = *(const f32x4*)&bias[c0];
        float scl = (c0 < CDIM) ? ATTSCALE : 1.f;
        s16x4 o;
        #pragma unroll
        for (int i = 0; i < 4; i++) o[i] = f2bfs((v[i] + b4[i]) * scl);
        *(s16x4*)&outb[(size_t)r*QKVC + c0] = o;
      }
    } else if constexpr (EPI == 1) {
      int b_ = r / NTOK, nn = r % NTOK;
      int b = b_ >> 4, wi = b_ & 15, wh = wi >> 2, ww = wi & 3;
      int ii = nn / WSZ, jj = nn % WSZ;
      int hh = (wh*WSZ + ii + SSZ) % HDIM;
      int wcc = (ww*WSZ + jj + SSZ) % WDIM;
      size_t rr = ((size_t)b*LDIM + hh*WDIM + wcc) * CDIM;
      #pragma unroll
      for (int n = 0; n < 4; n++) {
        int c0 = cb + n*16;
        f32x4 v = acc[n][m];
        f32x4 b4 = *(const f32x4*)&bias[c0];
        f32x4 a4 = *(const f32x4*)&aux[rr + c0];
        s16x4 o;
        #pragma unroll
        for (int i = 0; i < 4; i++) o[i] = f2bfs(a4[i] + v[i] + b4[i]);
        *(s16x4*)&outb[rr + c0] = o;
      }
    } else if constexpr (EPI == 2) {
      #pragma unroll
      for (int n = 0; n < 4; n++) {
        int c0 = cb + n*16;
        f32x4 v = acc[n][m];
        f32x4 b4 = *(const f32x4*)&bias[c0];
        s16x4 o;
        #pragma unroll
        for (int i = 0; i < 4; i++) {
          float val = v[i] + b4[i];
          val = 0.5f * val * (1.0f + erff(val * 0.70710678118654752f));
          o[i] = f2bfs(val);
        }
        *(s16x4*)&outb[(size_t)r*HIDDIM + c0] = o;
      }
    } else {
      #pragma unroll
      for (int n = 0; n < 4; n++) {
        int c0 = cb + n*16;
        f32x4 v = acc[n][m];
        f32x4 b4 = *(const f32x4*)&bias[c0];
        s16x4 ab = *(const s16x4*)&auxb[(size_t)r*CDIM + c0];
        f32x4 o;
        #pragma unroll
        for (int i = 0; i < 4; i++) o[i] = v[i] + b4[i] + bfs2f(ab[i]);
        *(f32x4*)&outf[(size_t)r*CDIM + c0] = o;
      }
    }
  }
}

// ---------------- MFMA fused window attention (round-11 proven form) ----------------
// Wave-independent strip loop (Ps wave-private); LDS tab2/regv gathers;
// wave-local lgkmcnt fence between P ds_writes and PV ds_reads.
__global__ __launch_bounds__(256) void k_attn_mfma(const bf16* __restrict__ qkv,
    const float* __restrict__ rt, bf16* __restrict__ out)
{
  __shared__ short  Ks[208*KROW];   // [m][k], rows 196..207 zero, padded stride
  __shared__ short  Vt[32*VROW];    // [d][m], cols 196..223 zero, padded stride
  __shared__ short  Ps[4][16*PROW]; // per-wave P strip [row][m], padded stride
  __shared__ float2 tab2[729];      // {bias, rscale} per rel-idx for this head
  __shared__ int    regv[208];

  int blk = blockIdx.x;
  int b_ = blk / NHEAD, head = blk % NHEAD;
  int tid = threadIdx.x, lane = tid & 63, wid = tid >> 6;
  int c15 = lane & 15, h4 = lane >> 4;

  // ---- staging ----
  const bf16* rowbase = qkv + (size_t)b_*NTOK*QKVC + head*HDHEAD;
  const bf16* kp = rowbase + CDIM;      // k block
  const bf16* vp = rowbase + 2*CDIM;    // v block
  for (int c = tid; c < 784; c += 256) {          // 196 rows x 4 chunks of 8
    int m = c >> 2, k8 = (c & 3) * 8;
    *(bf16x8*)&Ks[m*KROW + k8] = *(const bf16x8*)(kp + (size_t)m*QKVC + k8);
    bf16x8 vv = *(const bf16x8*)(vp + (size_t)m*QKVC + k8);
    #pragma unroll
    for (int j = 0; j < 8; j++) Vt[(k8+j)*VROW + m] = vv[j];
  }
  for (int e = tid; e < 12*KROW; e += 256) Ks[196*KROW + e] = 0;
  for (int e = tid; e < 32*28; e += 256) Vt[(e/28)*VROW + 196 + (e%28)] = 0;
  for (int e = tid; e < 729; e += 256)
    tab2[e] = make_float2(rt[e*2*NHEAD + head], rt[e*2*NHEAD + NHEAD + head]);
  {
    int wi = b_ & 15, wh = wi >> 2, ww = wi & 3;
    for (int e = tid; e < 208; e += 256) {
      int rv = 0;
      if (e < NTOK) {
        int i = e / WSZ, j = e % WSZ;
        int ha = wh*WSZ + i, wa = ww*WSZ + j;
        int rh = ha < (HDIM-WSZ) ? 0 : (ha < (HDIM-SSZ) ? 1 : 2);
        int rw = wa < (WDIM-WSZ) ? 0 : (wa < (WDIM-SSZ) ? 1 : 2);
        rv = rh*3 + rw;
      }
      regv[e] = rv;
    }
  }
  __syncthreads();

  // per-lane m-column constants (m = t*16 + c15)
  int   moff[13], mreg[13];
  float mpad[13];
  #pragma unroll
  for (int t = 0; t < 13; t++) {
    int m  = t*16 + c15;
    int mm = min(m, NTOK-1);
    moff[t] = (mm/WSZ)*27 + (mm%WSZ);
    mreg[t] = regv[mm];
    mpad[t] = (m >= NTOK) ? -1e30f : 0.f;
  }

  short* myP = &Ps[wid][0];
  // zero pad cols 208..223 once (never overwritten: softmax writes cols 0..207)
  #pragma unroll
  for (int i = 0; i < 4; i++) myP[(h4*4+i)*PROW + 208 + c15] = 0;

  bf16* op = out + (size_t)b_*NTOK*CDIM + head*HDHEAD;

  for (int s = wid; s < 13; s += 4) {             // wave-independent strips
    int qrow = min(s*16 + c15, NTOK-1);
    bf16x8 qf = *(const bf16x8*)(rowbase + (size_t)qrow*QKVC + h4*8);

    f32x4 sc[13];
    #pragma unroll
    for (int t = 0; t < 13; t++) {
      bf16x8 kf = *(const bf16x8*)&Ks[(t*16 + c15)*KROW + h4*8];
      sc[t] = __builtin_amdgcn_mfma_f32_16x16x32_bf16(qf, kf, (f32x4){0.f,0.f,0.f,0.f}, 0, 0, 0);
    }

    #pragma unroll
    for (int i = 0; i < 4; i++) {
      int n  = s*16 + h4*4 + i;
      int nc = min(n, NTOK-1);
      int nbase = ((nc/WSZ) + 13)*27 + (nc%WSZ) + 13;
      int nreg  = regv[nc];
      float rr[13];
      float sum = 0.f;
      #pragma unroll
      for (int t = 0; t < 13; t++) {
        float2 hr = tab2[nbase - moff[t]];
        float sv = sc[t][i] + hr.x + ((mreg[t] != nreg) ? -100.f : 0.f) + mpad[t];
        float e = __expf(sv);          // no-max softmax: |sv| tiny or -> 0
        rr[t] = hr.y;
        sc[t][i] = e; sum += e;
      }
      #pragma unroll
      for (int o = 1; o < 16; o <<= 1) sum += __shfl_xor(sum, o);
      float inv = 1.f / sum;
      int prow = h4*4 + i;
      #pragma unroll
      for (int t = 0; t < 13; t++)
        myP[prow*PROW + t*16 + c15] = f2bfs(sc[t][i] * inv * rr[t]);  // short store
    }

    // wave-local fence: drain this wave's P ds_writes before its PV ds_reads
    asm volatile("s_waitcnt lgkmcnt(0)" ::: "memory");
    __builtin_amdgcn_sched_barrier(0);

    // PV: O[16 x 32] = P[16 x 224] @ Vt^T
    f32x4 o0 = {0.f,0.f,0.f,0.f}, o1 = {0.f,0.f,0.f,0.f};
    #pragma unroll
    for (int t7 = 0; t7 < 7; t7++) {
      bf16x8 pf = *(const bf16x8*)&myP[c15*PROW + t7*32 + h4*8];
      bf16x8 v0 = *(const bf16x8*)&Vt[c15*VROW + t7*32 + h4*8];
      bf16x8 v1 = *(const bf16x8*)&Vt[(16 + c15)*VROW + t7*32 + h4*8];
      o0 = __builtin_amdgcn_mfma_f32_16x16x32_bf16(pf, v0, o0, 0, 0, 0);
      o1 = __builtin_amdgcn_mfma_f32_16x16x32_bf16(pf, v1, o1, 0, 0, 0);
    }

    #pragma unroll
    for (int i = 0; i < 4; i++) {
      int n = s*16 + h4*4 + i;
      if (n < NTOK) {
        op[(size_t)n*CDIM + c15]      = __float2bfloat16(o0[i]);
        op[(size_t)n*CDIM + 16 + c15] = __float2bfloat16(o1[i]);
      }
    }
  }
}

// ---------------- launch ----------------
extern "C" void kernel_launch(void* const* d_in, const int* in_sizes, int n_in,
                              void* d_out, int out_size, void* d_ws, size_t ws_size,
                              hipStream_t stream)
{
  const float* x      = (const float*)d_in[0];
  const float* n1w    = (const float*)d_in[1];
  const float* n1b    = (const float*)d_in[2];
  const float* qkv_w  = (const float*)d_in[3];
  const float* qkv_b  = (const float*)d_in[4];
  const float* proj_w = (const float*)d_in[5];
  const float* proj_b = (const float*)d_in[6];
  const float* rt     = (const float*)d_in[7];
  const float* n2w    = (const float*)d_in[8];
  const float* n2b    = (const float*)d_in[9];
  const float* fc1_w  = (const float*)d_in[10];
  const float* fc1_b  = (const float*)d_in[11];
  const float* fc2_w  = (const float*)d_in[12];
  const float* fc2_b  = (const float*)d_in[13];

  char* ws = (char*)d_ws;
  const size_t SZ_BF = (size_t)MROWS * CDIM * 2;   // 77,070,336 B
  // arena (total exactly 8*SZ_BF, proven footprint):
  //  R0 [0,1SZ):    xw -> attnout -> (after proj) wf1,wf2
  //  R1 [1SZ,4SZ):  qkv (contiguous [r][1152]) -> x2(bf16,[1SZ,2SZ)) + hln([2SZ,3SZ))
  //  R2 [4SZ,8SZ):  wq,wp (head) -> hid (overwrites dead wq/wp at fc1)
  bf16*  xw      = (bf16*)ws;
  bf16*  attnout = (bf16*)ws;
  bf16*  qkv     = (bf16*)(ws + SZ_BF);
  bf16*  x2b     = (bf16*)(ws + SZ_BF);
  bf16*  hln     = (bf16*)(ws + 2*SZ_BF);
  bf16*  hid     = (bf16*)(ws + 4*SZ_BF);
  const int NQKVW = 3*CDIM*CDIM;      // 442368
  const int NPROJW = CDIM*CDIM;       // 147456
  const int NFCW  = HIDDIM*CDIM;      // 589824
  bf16* wq  = (bf16*)(ws + 4*SZ_BF);  // lives in R2 until fc1 clobbers it
  bf16* wp  = wq + NQKVW;
  bf16* wf1 = (bf16*)ws;              // converted into R0 after proj GEMM
  bf16* wf2 = wf1 + NFCW;

  k_cvt<<<(NQKVW+255)/256, 256, 0, stream>>>(qkv_w, wq, NQKVW);
  k_cvt<<<(NPROJW+255)/256, 256, 0, stream>>>(proj_w, wp, NPROJW);

  k_ln<true, float><<<MROWS/4, 256, 0, stream>>>(x, n1w, n1b, xw);
  k_mgemm<CDIM, 0><<<(MROWS/256)*9, 512, 0, stream>>>(
      xw, wq, qkv_b, nullptr, nullptr, nullptr, qkv, 9);
  k_attn_mfma<<<BWIN*NHEAD, 256, 0, stream>>>(qkv, rt, attnout);
  k_mgemm<CDIM, 1><<<(MROWS/256)*3, 512, 0, stream>>>(
      attnout, wp, proj_b, x, nullptr, nullptr, x2b, 3);

  k_cvt<<<(NFCW+255)/256, 256, 0, stream>>>(fc1_w, wf1, NFCW);
  k_cvt<<<(NFCW+255)/256, 256, 0, stream>>>(fc2_w, wf2, NFCW);

  k_ln<false, bf16><<<MROWS/4, 256, 0, stream>>>(x2b, n2w, n2b, hln);
  k_mgemm<CDIM, 2><<<(MROWS/256)*12, 512, 0, stream>>>(
      hln, wf1, fc1_b, nullptr, nullptr, nullptr, hid, 12);
  k_mgemm<HIDDIM, 3><<<(MROWS/256)*3, 512, 0, stream>>>(
      hid, wf2, fc2_b, nullptr, x2b, (float*)d_out, nullptr, 3);
}